// Round 1
// baseline (3996.254 us; speedup 1.0000x reference)
//
#include <hip/hip_runtime.h>

constexpr int NN = 100000;   // nodes
constexpr int NE = 1600000;  // edges
constexpr int DI = 256, DH = 128, DO = 40;

// ---------------- GEMM1: h1[NN,128] = x[NN,256] @ W1[256,128] ----------------
// 64x128 output tile per block, BK=32, 256 threads, 4x8 register tile/thread.
__global__ __launch_bounds__(256) void gemm1_kernel(const float* __restrict__ x,
                                                    const float* __restrict__ W,
                                                    float* __restrict__ h1) {
    __shared__ float As[64][33];   // +1 pad breaks bank conflicts on A reads
    __shared__ float Bs[32][128];
    const int t = threadIdx.x;
    const int row0 = blockIdx.x * 64;
    const int tr = t >> 4;         // 0..15 -> rows tr*4..tr*4+3
    const int tc = t & 15;         // 0..15 -> cols tc*8..tc*8+7
    float acc[4][8] = {};

    for (int kc = 0; kc < DI; kc += 32) {
        // stage A tile 64x32 (2 float4 per thread)
        const int ar = t >> 3;            // 0..31
        const int ak = (t & 7) * 4;       // 0,4,..,28
        #pragma unroll
        for (int rr = 0; rr < 64; rr += 32) {
            const int gr = row0 + ar + rr;
            float4 v = make_float4(0.f, 0.f, 0.f, 0.f);
            if (gr < NN) v = *(const float4*)(x + (size_t)gr * DI + kc + ak);
            As[ar + rr][ak + 0] = v.x; As[ar + rr][ak + 1] = v.y;
            As[ar + rr][ak + 2] = v.z; As[ar + rr][ak + 3] = v.w;
        }
        // stage B tile 32x128 (4 float4 per thread)
        const int bk = t >> 5;            // 0..7
        const int bn = (t & 31) * 4;      // 0,4,..,124
        #pragma unroll
        for (int kk = 0; kk < 32; kk += 8) {
            *(float4*)(&Bs[bk + kk][bn]) =
                *(const float4*)(W + (size_t)(kc + bk + kk) * DH + bn);
        }
        __syncthreads();
        #pragma unroll
        for (int kk = 0; kk < 32; ++kk) {
            float a[4], b[8];
            #pragma unroll
            for (int i = 0; i < 4; ++i) a[i] = As[tr * 4 + i][kk];
            #pragma unroll
            for (int j = 0; j < 8; ++j) b[j] = Bs[kk][tc * 8 + j];
            #pragma unroll
            for (int i = 0; i < 4; ++i)
                #pragma unroll
                for (int j = 0; j < 8; ++j) acc[i][j] += a[i] * b[j];
        }
        __syncthreads();
    }
    #pragma unroll
    for (int i = 0; i < 4; ++i) {
        const int gr = row0 + tr * 4 + i;
        if (gr < NN) {
            *(float4*)(h1 + (size_t)gr * DH + tc * 8) =
                make_float4(acc[i][0], acc[i][1], acc[i][2], acc[i][3]);
            *(float4*)(h1 + (size_t)gr * DH + tc * 8 + 4) =
                make_float4(acc[i][4], acc[i][5], acc[i][6], acc[i][7]);
        }
    }
}

// ---------------- Scatter1: agg[dst] += h1[src], d=128 ----------------
// One thread per (edge, 4-channel group): 32 threads cover one edge's row.
__global__ __launch_bounds__(256) void scatter1_kernel(const float* __restrict__ h1,
                                                       const int* __restrict__ src,
                                                       const int* __restrict__ dst,
                                                       float* __restrict__ agg) {
    const int tid = blockIdx.x * 256 + threadIdx.x;
    const int e = tid >> 5;
    if (e >= NE) return;
    const int g = (tid & 31) * 4;
    const int s = src[e], d = dst[e];
    const float4 v = *(const float4*)(h1 + (size_t)s * DH + g);
    float* p = agg + (size_t)d * DH + g;
    atomicAdd(p + 0, v.x); atomicAdd(p + 1, v.y);
    atomicAdd(p + 2, v.z); atomicAdd(p + 3, v.w);
}

// ---------------- GEMM2: h2[NN,40] = relu(agg)[NN,128] @ W2[128,40] ----------------
// 8 rows per block, 320 threads = one thread per (row, col) output.
__global__ __launch_bounds__(320) void gemm2_kernel(const float* __restrict__ agg,
                                                    const float* __restrict__ W2,
                                                    float* __restrict__ h2) {
    __shared__ float rows[8][DH];
    const int t = threadIdx.x;
    const int r0 = blockIdx.x * 8;
    for (int i = t; i < 8 * DH; i += 320) {
        const int r = i >> 7, c = i & 127;
        float v = 0.f;
        if (r0 + r < NN) v = agg[(size_t)(r0 + r) * DH + c];
        rows[r][c] = fmaxf(v, 0.f);   // fused ReLU
    }
    __syncthreads();
    const int r = t / DO, c = t % DO;   // r in 0..7
    if (r0 + r < NN) {
        float s = 0.f;
        #pragma unroll 8
        for (int k = 0; k < DH; ++k) s += rows[r][k] * W2[k * DO + c];
        h2[(size_t)(r0 + r) * DO + c] = s;
    }
}

// ---------------- Scatter2: out[dst] += h2[src], d=40 ----------------
// One thread per (edge, 4-channel group): 10 threads per edge.
__global__ __launch_bounds__(256) void scatter2_kernel(const float* __restrict__ h2,
                                                       const int* __restrict__ src,
                                                       const int* __restrict__ dst,
                                                       float* __restrict__ out) {
    const int tid = blockIdx.x * 256 + threadIdx.x;
    const int e = tid / 10;
    if (e >= NE) return;
    const int g = (tid % 10) * 4;
    const int s = src[e], d = dst[e];
    const float4 v = *(const float4*)(h2 + (size_t)s * DO + g);
    float* p = out + (size_t)d * DO + g;
    atomicAdd(p + 0, v.x); atomicAdd(p + 1, v.y);
    atomicAdd(p + 2, v.z); atomicAdd(p + 3, v.w);
}

extern "C" void kernel_launch(void* const* d_in, const int* in_sizes, int n_in,
                              void* d_out, int out_size, void* d_ws, size_t ws_size,
                              hipStream_t stream) {
    const float* x  = (const float*)d_in[0];
    const int*   ei = (const int*)d_in[1];   // [2, NE] row-major: src then dst
    const float* W1 = (const float*)d_in[2];
    const float* W2 = (const float*)d_in[3];
    const int* src = ei;
    const int* dst = ei + NE;

    float* h1  = (float*)d_ws;                    // NN*128 fp32 = 51.2 MB
    float* agg = h1 + (size_t)NN * DH;            // NN*128 fp32 = 51.2 MB
    float* h2  = agg + (size_t)NN * DH;           // NN*40  fp32 = 16 MB
    float* out = (float*)d_out;

    hipMemsetAsync(agg, 0, (size_t)NN * DH * sizeof(float), stream);
    hipMemsetAsync(out, 0, (size_t)NN * DO * sizeof(float), stream);

    gemm1_kernel<<<(NN + 63) / 64, 256, 0, stream>>>(x, W1, h1);
    scatter1_kernel<<<(NE * 32 + 255) / 256, 256, 0, stream>>>(h1, src, dst, agg);
    gemm2_kernel<<<(NN + 7) / 8, 320, 0, stream>>>(agg, W2, h2);
    scatter2_kernel<<<(NE * 10 + 255) / 256, 256, 0, stream>>>(h2, src, dst, out);
}

// Round 2
// 943.979 us; speedup vs baseline: 4.2334x; 4.2334x over previous
//
#include <hip/hip_runtime.h>

constexpr int NN = 100000;   // nodes
constexpr int NE = 1600000;  // edges
constexpr int DI = 256, DH = 128, DO = 40;

// ---------------- GEMM1: h1[NN,128] = x[NN,256] @ W1[256,128] ----------------
__global__ __launch_bounds__(256) void gemm1_kernel(const float* __restrict__ x,
                                                    const float* __restrict__ W,
                                                    float* __restrict__ h1) {
    __shared__ float As[64][33];
    __shared__ float Bs[32][128];
    const int t = threadIdx.x;
    const int row0 = blockIdx.x * 64;
    const int tr = t >> 4;
    const int tc = t & 15;
    float acc[4][8] = {};

    for (int kc = 0; kc < DI; kc += 32) {
        const int ar = t >> 3;
        const int ak = (t & 7) * 4;
        #pragma unroll
        for (int rr = 0; rr < 64; rr += 32) {
            const int gr = row0 + ar + rr;
            float4 v = make_float4(0.f, 0.f, 0.f, 0.f);
            if (gr < NN) v = *(const float4*)(x + (size_t)gr * DI + kc + ak);
            As[ar + rr][ak + 0] = v.x; As[ar + rr][ak + 1] = v.y;
            As[ar + rr][ak + 2] = v.z; As[ar + rr][ak + 3] = v.w;
        }
        const int bk = t >> 5;
        const int bn = (t & 31) * 4;
        #pragma unroll
        for (int kk = 0; kk < 32; kk += 8) {
            *(float4*)(&Bs[bk + kk][bn]) =
                *(const float4*)(W + (size_t)(kc + bk + kk) * DH + bn);
        }
        __syncthreads();
        #pragma unroll
        for (int kk = 0; kk < 32; ++kk) {
            float a[4], b[8];
            #pragma unroll
            for (int i = 0; i < 4; ++i) a[i] = As[tr * 4 + i][kk];
            #pragma unroll
            for (int j = 0; j < 8; ++j) b[j] = Bs[kk][tc * 8 + j];
            #pragma unroll
            for (int i = 0; i < 4; ++i)
                #pragma unroll
                for (int j = 0; j < 8; ++j) acc[i][j] += a[i] * b[j];
        }
        __syncthreads();
    }
    #pragma unroll
    for (int i = 0; i < 4; ++i) {
        const int gr = row0 + tr * 4 + i;
        if (gr < NN) {
            *(float4*)(h1 + (size_t)gr * DH + tc * 8) =
                make_float4(acc[i][0], acc[i][1], acc[i][2], acc[i][3]);
            *(float4*)(h1 + (size_t)gr * DH + tc * 8 + 4) =
                make_float4(acc[i][4], acc[i][5], acc[i][6], acc[i][7]);
        }
    }
}

// ---------------- CSR build: counting sort of edges by dst ----------------
__global__ __launch_bounds__(256) void hist_kernel(const int* __restrict__ dst,
                                                   int* __restrict__ deg) {
    const int e = blockIdx.x * 256 + threadIdx.x;
    if (e < NE) atomicAdd(&deg[dst[e]], 1);
}

// Single-block exclusive scan over deg[0..NN) -> off[0..NN], also copy to cur.
__global__ __launch_bounds__(1024) void scan_kernel(const int* __restrict__ deg,
                                                    int* __restrict__ off,
                                                    int* __restrict__ cur) {
    __shared__ int part[1024];
    const int t = threadIdx.x;
    const int chunk = (NN + 1023) / 1024;   // 98
    const int base = t * chunk;
    int s = 0;
    for (int i = 0; i < chunk; ++i) {
        const int idx = base + i;
        if (idx < NN) s += deg[idx];
    }
    part[t] = s;
    __syncthreads();
    // Hillis-Steele inclusive scan
    for (int d = 1; d < 1024; d <<= 1) {
        int v = (t >= d) ? part[t - d] : 0;
        __syncthreads();
        part[t] += v;
        __syncthreads();
    }
    int run = (t == 0) ? 0 : part[t - 1];
    for (int i = 0; i < chunk; ++i) {
        const int idx = base + i;
        if (idx < NN) {
            off[idx] = run;
            cur[idx] = run;
            run += deg[idx];
        }
    }
    if (t == 1023) off[NN] = part[1023];   // total = NE
}

// esrc[pos] = src of each edge, grouped by dst
__global__ __launch_bounds__(256) void edge_scatter_kernel(const int* __restrict__ src,
                                                           const int* __restrict__ dst,
                                                           int* __restrict__ cur,
                                                           int* __restrict__ esrc) {
    const int e = blockIdx.x * 256 + threadIdx.x;
    if (e >= NE) return;
    const int p = atomicAdd(&cur[dst[e]], 1);
    esrc[p] = src[e];
}

// ---------------- Agg1: agg[n] = relu(sum_{e: dst=n} h1[src_e]), d=128 ----------------
// One wave per node; lane owns 2 channels (float2) -> 512 B contiguous row reads.
__global__ __launch_bounds__(256) void agg1_kernel(const float* __restrict__ h1,
                                                   const int* __restrict__ esrc,
                                                   const int* __restrict__ off,
                                                   float* __restrict__ agg) {
    const int w = (blockIdx.x * 256 + threadIdx.x) >> 6;   // node id
    if (w >= NN) return;
    const int lane = threadIdx.x & 63;
    const int b = off[w], e = off[w + 1];
    float2 acc = make_float2(0.f, 0.f);
    int j = b;
    for (; j + 1 < e; j += 2) {   // unroll 2 for load ILP
        const int s0 = esrc[j], s1 = esrc[j + 1];
        const float2 v0 = *(const float2*)(h1 + (size_t)s0 * DH + lane * 2);
        const float2 v1 = *(const float2*)(h1 + (size_t)s1 * DH + lane * 2);
        acc.x += v0.x + v1.x;
        acc.y += v0.y + v1.y;
    }
    if (j < e) {
        const int s0 = esrc[j];
        const float2 v0 = *(const float2*)(h1 + (size_t)s0 * DH + lane * 2);
        acc.x += v0.x;
        acc.y += v0.y;
    }
    *(float2*)(agg + (size_t)w * DH + lane * 2) =
        make_float2(fmaxf(acc.x, 0.f), fmaxf(acc.y, 0.f));   // fused ReLU
}

// ---------------- GEMM2: h2[NN,40] = agg[NN,128] @ W2[128,40] ----------------
// (agg already ReLU'd)
__global__ __launch_bounds__(320) void gemm2_kernel(const float* __restrict__ agg,
                                                    const float* __restrict__ W2,
                                                    float* __restrict__ h2) {
    __shared__ float rows[8][DH];
    const int t = threadIdx.x;
    const int r0 = blockIdx.x * 8;
    for (int i = t; i < 8 * DH; i += 320) {
        const int r = i >> 7, c = i & 127;
        float v = 0.f;
        if (r0 + r < NN) v = agg[(size_t)(r0 + r) * DH + c];
        rows[r][c] = v;
    }
    __syncthreads();
    const int r = t / DO, c = t % DO;
    if (r0 + r < NN) {
        float s = 0.f;
        #pragma unroll 8
        for (int k = 0; k < DH; ++k) s += rows[r][k] * W2[k * DO + c];
        h2[(size_t)(r0 + r) * DO + c] = s;
    }
}

// ---------------- Agg2: out[n] = sum_{e: dst=n} h2[src_e], d=40 ----------------
// One wave per node; lanes 0..39 own one channel each.
__global__ __launch_bounds__(256) void agg2_kernel(const float* __restrict__ h2,
                                                   const int* __restrict__ esrc,
                                                   const int* __restrict__ off,
                                                   float* __restrict__ out) {
    const int w = (blockIdx.x * 256 + threadIdx.x) >> 6;   // node id
    if (w >= NN) return;
    const int lane = threadIdx.x & 63;
    if (lane >= DO) return;
    const int b = off[w], e = off[w + 1];
    float acc = 0.f;
    int j = b;
    for (; j + 1 < e; j += 2) {
        const int s0 = esrc[j], s1 = esrc[j + 1];
        acc += h2[(size_t)s0 * DO + lane] + h2[(size_t)s1 * DO + lane];
    }
    if (j < e) acc += h2[(size_t)esrc[j] * DO + lane];
    out[(size_t)w * DO + lane] = acc;
}

extern "C" void kernel_launch(void* const* d_in, const int* in_sizes, int n_in,
                              void* d_out, int out_size, void* d_ws, size_t ws_size,
                              hipStream_t stream) {
    const float* x  = (const float*)d_in[0];
    const int*   ei = (const int*)d_in[1];
    const float* W1 = (const float*)d_in[2];
    const float* W2 = (const float*)d_in[3];
    const int* src = ei;
    const int* dst = ei + NE;

    // Workspace layout (~110 MB; h2 aliases h1 which is dead after agg1)
    float* h1  = (float*)d_ws;                       // NN*128 f32 = 51.2 MB
    float* agg = h1 + (size_t)NN * DH;               // NN*128 f32 = 51.2 MB
    float* h2  = h1;                                 // NN*40 f32 (aliases h1)
    int* ints  = (int*)(agg + (size_t)NN * DH);
    int* deg  = ints;                                // NN
    int* off  = deg + NN;                            // NN+1
    int* cur  = off + NN + 1;                        // NN
    int* esrc = cur + NN;                            // NE

    float* out = (float*)d_out;

    hipMemsetAsync(deg, 0, NN * sizeof(int), stream);

    gemm1_kernel<<<(NN + 63) / 64, 256, 0, stream>>>(x, W1, h1);
    hist_kernel<<<(NE + 255) / 256, 256, 0, stream>>>(dst, deg);
    scan_kernel<<<1, 1024, 0, stream>>>(deg, off, cur);
    edge_scatter_kernel<<<(NE + 255) / 256, 256, 0, stream>>>(src, dst, cur, esrc);
    agg1_kernel<<<(NN * 64 + 255) / 256, 256, 0, stream>>>(h1, esrc, off, agg);
    gemm2_kernel<<<(NN + 7) / 8, 320, 0, stream>>>(agg, W2, h2);
    agg2_kernel<<<(NN * 64 + 255) / 256, 256, 0, stream>>>(h2, esrc, off, out);
}

// Round 3
// 656.567 us; speedup vs baseline: 6.0866x; 1.4377x over previous
//
#include <hip/hip_runtime.h>

constexpr int NN = 100000;   // nodes
constexpr int NE = 1600000;  // edges
constexpr int DI = 256, DH = 128, DO = 40;

constexpr int SCAN_CHUNK = 1024;
constexpr int NB_SCAN = (NN + SCAN_CHUNK - 1) / SCAN_CHUNK;   // 98

// ---------------- GEMM1: h1[NN,128] = x[NN,256] @ W1[256,128] ----------------
__global__ __launch_bounds__(256) void gemm1_kernel(const float* __restrict__ x,
                                                    const float* __restrict__ W,
                                                    float* __restrict__ h1) {
    __shared__ float As[64][33];
    __shared__ float Bs[32][128];
    const int t = threadIdx.x;
    const int row0 = blockIdx.x * 64;
    const int tr = t >> 4;
    const int tc = t & 15;
    float acc[4][8] = {};

    for (int kc = 0; kc < DI; kc += 32) {
        const int ar = t >> 3;
        const int ak = (t & 7) * 4;
        #pragma unroll
        for (int rr = 0; rr < 64; rr += 32) {
            const int gr = row0 + ar + rr;
            float4 v = make_float4(0.f, 0.f, 0.f, 0.f);
            if (gr < NN) v = *(const float4*)(x + (size_t)gr * DI + kc + ak);
            As[ar + rr][ak + 0] = v.x; As[ar + rr][ak + 1] = v.y;
            As[ar + rr][ak + 2] = v.z; As[ar + rr][ak + 3] = v.w;
        }
        const int bk = t >> 5;
        const int bn = (t & 31) * 4;
        #pragma unroll
        for (int kk = 0; kk < 32; kk += 8) {
            *(float4*)(&Bs[bk + kk][bn]) =
                *(const float4*)(W + (size_t)(kc + bk + kk) * DH + bn);
        }
        __syncthreads();
        #pragma unroll
        for (int kk = 0; kk < 32; ++kk) {
            float a[4], b[8];
            #pragma unroll
            for (int i = 0; i < 4; ++i) a[i] = As[tr * 4 + i][kk];
            #pragma unroll
            for (int j = 0; j < 8; ++j) b[j] = Bs[kk][tc * 8 + j];
            #pragma unroll
            for (int i = 0; i < 4; ++i)
                #pragma unroll
                for (int j = 0; j < 8; ++j) acc[i][j] += a[i] * b[j];
        }
        __syncthreads();
    }
    #pragma unroll
    for (int i = 0; i < 4; ++i) {
        const int gr = row0 + tr * 4 + i;
        if (gr < NN) {
            *(float4*)(h1 + (size_t)gr * DH + tc * 8) =
                make_float4(acc[i][0], acc[i][1], acc[i][2], acc[i][3]);
            *(float4*)(h1 + (size_t)gr * DH + tc * 8 + 4) =
                make_float4(acc[i][4], acc[i][5], acc[i][6], acc[i][7]);
        }
    }
}

// ---------------- CSR build ----------------
__global__ __launch_bounds__(256) void hist_kernel(const int* __restrict__ dst,
                                                   int* __restrict__ deg) {
    const int e = blockIdx.x * 256 + threadIdx.x;
    if (e < NE) atomicAdd(&deg[dst[e]], 1);
}

// phase 1: per-block (1024-element chunk) sums
__global__ __launch_bounds__(256) void scan_part_kernel(const int* __restrict__ deg,
                                                        int* __restrict__ blocksum) {
    __shared__ int red[256];
    const int t = threadIdx.x;
    const int idx = blockIdx.x * SCAN_CHUNK + t * 4;
    int s = 0;
    if (idx < NN) {
        const int4 v = *(const int4*)(deg + idx);
        s = v.x + v.y + v.z + v.w;
    }
    red[t] = s;
    __syncthreads();
    #pragma unroll
    for (int d = 128; d > 0; d >>= 1) {
        if (t < d) red[t] += red[t + d];
        __syncthreads();
    }
    if (t == 0) blocksum[blockIdx.x] = red[0];
}

// phase 2: scan the 98 block sums (one tiny block); also writes off[NN]=NE
__global__ __launch_bounds__(128) void scan_block_kernel(const int* __restrict__ blocksum,
                                                         int* __restrict__ blockoff,
                                                         int* __restrict__ off) {
    __shared__ int part[128];
    const int t = threadIdx.x;
    const int v = (t < NB_SCAN) ? blocksum[t] : 0;
    part[t] = v;
    __syncthreads();
    for (int d = 1; d < 128; d <<= 1) {
        const int u = (t >= d) ? part[t - d] : 0;
        __syncthreads();
        part[t] += u;
        __syncthreads();
    }
    if (t < NB_SCAN) blockoff[t] = part[t] - v;   // exclusive
    if (t == 0) off[NN] = NE;
}

// phase 3: local scan + block offset -> off, cur
__global__ __launch_bounds__(256) void scan_final_kernel(const int* __restrict__ deg,
                                                         const int* __restrict__ blockoff,
                                                         int* __restrict__ off,
                                                         int* __restrict__ cur) {
    __shared__ int part[256];
    const int t = threadIdx.x;
    const int idx = blockIdx.x * SCAN_CHUNK + t * 4;
    int4 v = make_int4(0, 0, 0, 0);
    if (idx < NN) v = *(const int4*)(deg + idx);
    const int s = v.x + v.y + v.z + v.w;
    part[t] = s;
    __syncthreads();
    for (int d = 1; d < 256; d <<= 1) {
        const int u = (t >= d) ? part[t - d] : 0;
        __syncthreads();
        part[t] += u;
        __syncthreads();
    }
    if (idx < NN) {
        const int base = blockoff[blockIdx.x] + part[t] - s;   // exclusive prefix
        const int o0 = base, o1 = o0 + v.x, o2 = o1 + v.y, o3 = o2 + v.z;
        const int4 ov = make_int4(o0, o1, o2, o3);
        *(int4*)(off + idx) = ov;
        *(int4*)(cur + idx) = ov;
    }
}

__global__ __launch_bounds__(256) void edge_scatter_kernel(const int* __restrict__ src,
                                                           const int* __restrict__ dst,
                                                           int* __restrict__ cur,
                                                           int* __restrict__ esrc) {
    const int e = blockIdx.x * 256 + threadIdx.x;
    if (e >= NE) return;
    const int p = atomicAdd(&cur[dst[e]], 1);
    esrc[p] = src[e];
}

// ---------------- Agg1: agg[n] = relu(sum h1[src_e]), d=128 ----------------
// One wave per node; half-wave per edge (32 lanes x float4 = one 512B row),
// 2 edges in flight per iteration, shfl_xor(32) combine.
__global__ __launch_bounds__(256) void agg1_kernel(const float* __restrict__ h1,
                                                   const int* __restrict__ esrc,
                                                   const int* __restrict__ off,
                                                   float* __restrict__ agg) {
    const int w = (blockIdx.x * 256 + threadIdx.x) >> 6;
    if (w >= NN) return;
    const int lane = threadIdx.x & 63;
    const int half = lane >> 5;
    const int c = (lane & 31) * 4;
    const int b = off[w], e = off[w + 1];
    float4 acc = make_float4(0.f, 0.f, 0.f, 0.f);
    for (int j = b + half; j < e; j += 2) {
        const int s = esrc[j];
        const float4 v = *(const float4*)(h1 + (size_t)s * DH + c);
        acc.x += v.x; acc.y += v.y; acc.z += v.z; acc.w += v.w;
    }
    acc.x += __shfl_xor(acc.x, 32);
    acc.y += __shfl_xor(acc.y, 32);
    acc.z += __shfl_xor(acc.z, 32);
    acc.w += __shfl_xor(acc.w, 32);
    if (half == 0) {
        *(float4*)(agg + (size_t)w * DH + c) =
            make_float4(fmaxf(acc.x, 0.f), fmaxf(acc.y, 0.f),
                        fmaxf(acc.z, 0.f), fmaxf(acc.w, 0.f));
    }
}

// ---------------- GEMM2: h2[NN,40] = agg[NN,128] @ W2[128,40] ----------------
__global__ __launch_bounds__(320) void gemm2_kernel(const float* __restrict__ agg,
                                                    const float* __restrict__ W2,
                                                    float* __restrict__ h2) {
    __shared__ float rows[8][DH];
    const int t = threadIdx.x;
    const int r0 = blockIdx.x * 8;
    for (int i = t; i < 8 * DH; i += 320) {
        const int r = i >> 7, c = i & 127;
        float v = 0.f;
        if (r0 + r < NN) v = agg[(size_t)(r0 + r) * DH + c];
        rows[r][c] = v;
    }
    __syncthreads();
    const int r = t / DO, c = t % DO;
    if (r0 + r < NN) {
        float s = 0.f;
        #pragma unroll 8
        for (int k = 0; k < DH; ++k) s += rows[r][k] * W2[k * DO + c];
        h2[(size_t)(r0 + r) * DO + c] = s;
    }
}

// ---------------- Agg2: out[n] = sum h2[src_e], d=40 ----------------
// One wave per node; 10 lanes x float4 = one 160B row, 6 edges per iteration
// (lanes 60..63 idle), 2-step shuffle reduce over the 6 sub-accumulators.
__global__ __launch_bounds__(256) void agg2_kernel(const float* __restrict__ h2,
                                                   const int* __restrict__ esrc,
                                                   const int* __restrict__ off,
                                                   float* __restrict__ out) {
    const int w = (blockIdx.x * 256 + threadIdx.x) >> 6;
    if (w >= NN) return;
    const int lane = threadIdx.x & 63;
    const int sub = lane / 10;          // 0..5 active, 6 = idle lanes 60..63
    const int c = (lane % 10) * 4;
    const int b = off[w], e = off[w + 1];
    float4 acc = make_float4(0.f, 0.f, 0.f, 0.f);
    if (sub < 6) {
        for (int j = b + sub; j < e; j += 6) {
            const int s = esrc[j];
            const float4 v = *(const float4*)(h2 + (size_t)s * DO + c);
            acc.x += v.x; acc.y += v.y; acc.z += v.z; acc.w += v.w;
        }
    }
    // fold subs 3..5 onto 0..2 (lanes l += lane l+30)
    acc.x += __shfl(acc.x, lane + 30);
    acc.y += __shfl(acc.y, lane + 30);
    acc.z += __shfl(acc.z, lane + 30);
    acc.w += __shfl(acc.w, lane + 30);
    // lanes 0..9: add combined sub1 (l+10) and sub2 (l+20)
    const float ax = acc.x + __shfl(acc.x, lane + 10) + __shfl(acc.x, lane + 20);
    const float ay = acc.y + __shfl(acc.y, lane + 10) + __shfl(acc.y, lane + 20);
    const float az = acc.z + __shfl(acc.z, lane + 10) + __shfl(acc.z, lane + 20);
    const float aw = acc.w + __shfl(acc.w, lane + 10) + __shfl(acc.w, lane + 20);
    if (lane < 10) {
        *(float4*)(out + (size_t)w * DO + c) = make_float4(ax, ay, az, aw);
    }
}

extern "C" void kernel_launch(void* const* d_in, const int* in_sizes, int n_in,
                              void* d_out, int out_size, void* d_ws, size_t ws_size,
                              hipStream_t stream) {
    const float* x  = (const float*)d_in[0];
    const int*   ei = (const int*)d_in[1];
    const float* W1 = (const float*)d_in[2];
    const float* W2 = (const float*)d_in[3];
    const int* src = ei;
    const int* dst = ei + NE;

    float* h1  = (float*)d_ws;                       // NN*128 f32 = 51.2 MB
    float* agg = h1 + (size_t)NN * DH;               // NN*128 f32 = 51.2 MB
    float* h2  = h1;                                 // NN*40 f32 (aliases h1; h1 dead after agg1)
    int* ints  = (int*)(agg + (size_t)NN * DH);
    int* deg      = ints;                            // NN
    int* off      = deg + NN;                        // NN+1
    int* cur      = off + NN + 1;                    // NN
    int* esrc     = cur + NN;                        // NE
    int* blocksum = esrc + NE;                       // NB_SCAN
    int* blockoff = blocksum + NB_SCAN;              // NB_SCAN

    float* out = (float*)d_out;

    hipMemsetAsync(deg, 0, NN * sizeof(int), stream);

    gemm1_kernel<<<(NN + 63) / 64, 256, 0, stream>>>(x, W1, h1);
    hist_kernel<<<(NE + 255) / 256, 256, 0, stream>>>(dst, deg);
    scan_part_kernel<<<NB_SCAN, 256, 0, stream>>>(deg, blocksum);
    scan_block_kernel<<<1, 128, 0, stream>>>(blocksum, blockoff, off);
    scan_final_kernel<<<NB_SCAN, 256, 0, stream>>>(deg, blockoff, off, cur);
    edge_scatter_kernel<<<(NE + 255) / 256, 256, 0, stream>>>(src, dst, cur, esrc);
    agg1_kernel<<<(NN * 64 + 255) / 256, 256, 0, stream>>>(h1, esrc, off, agg);
    gemm2_kernel<<<(NN + 7) / 8, 320, 0, stream>>>(agg, W2, h2);
    agg2_kernel<<<(NN * 64 + 255) / 256, 256, 0, stream>>>(h2, esrc, off, out);
}

// Round 4
// 541.966 us; speedup vs baseline: 7.3736x; 1.2115x over previous
//
#include <hip/hip_runtime.h>

constexpr int NN = 100000;   // nodes
constexpr int NE = 1600000;  // edges
constexpr int DI = 256, DH = 128, DO = 40;

// Bucket radix sort params
constexpr int NB = (NN + 255) >> 8;        // 391 buckets of 256 dst values
constexpr int NB_BLK = 128;                // blocks in hist/scatter passes
constexpr int CHUNK = NE / NB_BLK;         // 12500 edges per block (exact)
constexpr int M2 = NB * NB_BLK;            // 50048 hist entries
constexpr int NBS = (M2 + 1023) / 1024;    // 49 scan partials
constexpr int STAGE_CAP = 6144;            // bucket staging (avg load ~4092, max ~4400)

// ---------------- GEMM1: h1[NN,128] = x[NN,256] @ W1[256,128] ----------------
__global__ __launch_bounds__(256) void gemm1_kernel(const float* __restrict__ x,
                                                    const float* __restrict__ W,
                                                    float* __restrict__ h1) {
    __shared__ float As[64][33];
    __shared__ float Bs[32][128];
    const int t = threadIdx.x;
    const int row0 = blockIdx.x * 64;
    const int tr = t >> 4;
    const int tc = t & 15;
    float acc[4][8] = {};

    for (int kc = 0; kc < DI; kc += 32) {
        const int ar = t >> 3;
        const int ak = (t & 7) * 4;
        #pragma unroll
        for (int rr = 0; rr < 64; rr += 32) {
            const int gr = row0 + ar + rr;
            float4 v = make_float4(0.f, 0.f, 0.f, 0.f);
            if (gr < NN) v = *(const float4*)(x + (size_t)gr * DI + kc + ak);
            As[ar + rr][ak + 0] = v.x; As[ar + rr][ak + 1] = v.y;
            As[ar + rr][ak + 2] = v.z; As[ar + rr][ak + 3] = v.w;
        }
        const int bk = t >> 5;
        const int bn = (t & 31) * 4;
        #pragma unroll
        for (int kk = 0; kk < 32; kk += 8) {
            *(float4*)(&Bs[bk + kk][bn]) =
                *(const float4*)(W + (size_t)(kc + bk + kk) * DH + bn);
        }
        __syncthreads();
        #pragma unroll
        for (int kk = 0; kk < 32; ++kk) {
            float a[4], b[8];
            #pragma unroll
            for (int i = 0; i < 4; ++i) a[i] = As[tr * 4 + i][kk];
            #pragma unroll
            for (int j = 0; j < 8; ++j) b[j] = Bs[kk][tc * 8 + j];
            #pragma unroll
            for (int i = 0; i < 4; ++i)
                #pragma unroll
                for (int j = 0; j < 8; ++j) acc[i][j] += a[i] * b[j];
        }
        __syncthreads();
    }
    #pragma unroll
    for (int i = 0; i < 4; ++i) {
        const int gr = row0 + tr * 4 + i;
        if (gr < NN) {
            *(float4*)(h1 + (size_t)gr * DH + tc * 8) =
                make_float4(acc[i][0], acc[i][1], acc[i][2], acc[i][3]);
            *(float4*)(h1 + (size_t)gr * DH + tc * 8 + 4) =
                make_float4(acc[i][4], acc[i][5], acc[i][6], acc[i][7]);
        }
    }
}

// ---------------- P1: per-block bucket histogram ----------------
__global__ __launch_bounds__(256) void bucket_hist_kernel(const int* __restrict__ dst,
                                                          int* __restrict__ hist2d) {
    __shared__ int h[NB];
    for (int i = threadIdx.x; i < NB; i += 256) h[i] = 0;
    __syncthreads();
    const int base = blockIdx.x * CHUNK;
    for (int i = threadIdx.x; i < CHUNK; i += 256)
        atomicAdd(&h[dst[base + i] >> 8], 1);
    __syncthreads();
    for (int i = threadIdx.x; i < NB; i += 256)
        hist2d[i * NB_BLK + blockIdx.x] = h[i];   // bucket-major
}

// ---------------- scan of hist2d (M2 entries) ----------------
__global__ __launch_bounds__(256) void spart_kernel(const int* __restrict__ in,
                                                    int* __restrict__ bsum) {
    __shared__ int red[256];
    const int idx = blockIdx.x * 1024 + threadIdx.x * 4;
    int s = 0;
    if (idx < M2) { const int4 v = *(const int4*)(in + idx); s = v.x + v.y + v.z + v.w; }
    red[threadIdx.x] = s;
    __syncthreads();
    #pragma unroll
    for (int d = 128; d > 0; d >>= 1) {
        if (threadIdx.x < d) red[threadIdx.x] += red[threadIdx.x + d];
        __syncthreads();
    }
    if (threadIdx.x == 0) bsum[blockIdx.x] = red[0];
}

__global__ __launch_bounds__(64) void sblock_kernel(const int* __restrict__ bsum,
                                                    int* __restrict__ boff) {
    __shared__ int part[64];
    const int t = threadIdx.x;
    const int v = (t < NBS) ? bsum[t] : 0;
    part[t] = v;
    __syncthreads();
    for (int d = 1; d < 64; d <<= 1) {
        const int u = (t >= d) ? part[t - d] : 0;
        __syncthreads();
        part[t] += u;
        __syncthreads();
    }
    if (t < NBS) boff[t] = part[t] - v;
}

__global__ __launch_bounds__(256) void sfinal_kernel(const int* __restrict__ in,
                                                     const int* __restrict__ boff,
                                                     int* __restrict__ out) {
    __shared__ int part[256];
    const int t = threadIdx.x;
    const int idx = blockIdx.x * 1024 + t * 4;
    int4 v = make_int4(0, 0, 0, 0);
    if (idx < M2) v = *(const int4*)(in + idx);
    const int s = v.x + v.y + v.z + v.w;
    part[t] = s;
    __syncthreads();
    for (int d = 1; d < 256; d <<= 1) {
        const int u = (t >= d) ? part[t - d] : 0;
        __syncthreads();
        part[t] += u;
        __syncthreads();
    }
    if (idx < M2) {
        const int base = boff[blockIdx.x] + part[t] - s;
        *(int4*)(out + idx) = make_int4(base, base + v.x, base + v.x + v.y,
                                        base + v.x + v.y + v.z);
    }
}

// ---------------- P3: scatter pairs into bucket partitions ----------------
__global__ __launch_bounds__(256) void bucket_scatter_kernel(const int* __restrict__ src,
                                                             const int* __restrict__ dst,
                                                             const int* __restrict__ offs2d,
                                                             int2* __restrict__ epair) {
    __shared__ int cur[NB];
    for (int i = threadIdx.x; i < NB; i += 256)
        cur[i] = offs2d[i * NB_BLK + blockIdx.x];
    __syncthreads();
    const int base = blockIdx.x * CHUNK;
    for (int i = threadIdx.x; i < CHUNK; i += 256) {
        const int d = dst[base + i], s = src[base + i];
        const int p = atomicAdd(&cur[d >> 8], 1);
        epair[p] = make_int2(s, d);
    }
}

// ---------------- P4: within-bucket counting sort; emits off[] and esrc ----------------
__global__ __launch_bounds__(256) void bucket_sort_kernel(const int2* __restrict__ epair,
                                                          const int* __restrict__ offs2d,
                                                          int* __restrict__ off,
                                                          int* __restrict__ esrc) {
    __shared__ int cnt[256];
    __shared__ int incl[256];
    __shared__ int cur[256];
    __shared__ int stage[STAGE_CAP];
    const int b = blockIdx.x;
    const int t = threadIdx.x;
    const int bstart = offs2d[b * NB_BLK];
    const int bend = (b + 1 < NB) ? offs2d[(b + 1) * NB_BLK] : NE;
    const int n = bend - bstart;
    cnt[t] = 0;
    __syncthreads();
    for (int i = t; i < n; i += 256)
        atomicAdd(&cnt[epair[bstart + i].y & 255], 1);
    __syncthreads();
    incl[t] = cnt[t];
    __syncthreads();
    for (int d = 1; d < 256; d <<= 1) {
        const int u = (t >= d) ? incl[t - d] : 0;
        __syncthreads();
        incl[t] += u;
        __syncthreads();
    }
    const int ex = incl[t] - cnt[t];   // exclusive prefix within bucket
    const int node = (b << 8) + t;
    if (node <= NN) off[node] = bstart + ex;   // node==NN lands in bucket 390 -> off[NN]=NE
    cur[t] = ex;
    __syncthreads();
    const bool staged = (n <= STAGE_CAP);
    for (int i = t; i < n; i += 256) {
        const int2 pr = epair[bstart + i];
        const int p = atomicAdd(&cur[pr.y & 255], 1);
        if (staged) stage[p] = pr.x;
        else esrc[bstart + p] = pr.x;
    }
    __syncthreads();
    if (staged)
        for (int i = t; i < n; i += 256) esrc[bstart + i] = stage[i];
}

// ---------------- Agg1: agg[n] = relu(sum h1[src_e]), d=128 ----------------
__global__ __launch_bounds__(256) void agg1_kernel(const float* __restrict__ h1,
                                                   const int* __restrict__ esrc,
                                                   const int* __restrict__ off,
                                                   float* __restrict__ agg) {
    const int w = (blockIdx.x * 256 + threadIdx.x) >> 6;
    if (w >= NN) return;
    const int lane = threadIdx.x & 63;
    const int half = lane >> 5;
    const int c = (lane & 31) * 4;
    const int b = off[w], e = off[w + 1];
    float4 acc = make_float4(0.f, 0.f, 0.f, 0.f);
    for (int j = b + half; j < e; j += 2) {
        const int s = esrc[j];
        const float4 v = *(const float4*)(h1 + (size_t)s * DH + c);
        acc.x += v.x; acc.y += v.y; acc.z += v.z; acc.w += v.w;
    }
    acc.x += __shfl_xor(acc.x, 32);
    acc.y += __shfl_xor(acc.y, 32);
    acc.z += __shfl_xor(acc.z, 32);
    acc.w += __shfl_xor(acc.w, 32);
    if (half == 0) {
        *(float4*)(agg + (size_t)w * DH + c) =
            make_float4(fmaxf(acc.x, 0.f), fmaxf(acc.y, 0.f),
                        fmaxf(acc.z, 0.f), fmaxf(acc.w, 0.f));
    }
}

// ---------------- GEMM2: h2[NN,40] = agg[NN,128] @ W2[128,40] ----------------
__global__ __launch_bounds__(320) void gemm2_kernel(const float* __restrict__ agg,
                                                    const float* __restrict__ W2,
                                                    float* __restrict__ h2) {
    __shared__ float rows[8][DH];
    const int t = threadIdx.x;
    const int r0 = blockIdx.x * 8;
    for (int i = t; i < 8 * DH; i += 320) {
        const int r = i >> 7, c = i & 127;
        float v = 0.f;
        if (r0 + r < NN) v = agg[(size_t)(r0 + r) * DH + c];
        rows[r][c] = v;
    }
    __syncthreads();
    const int r = t / DO, c = t % DO;
    if (r0 + r < NN) {
        float s = 0.f;
        #pragma unroll 8
        for (int k = 0; k < DH; ++k) s += rows[r][k] * W2[k * DO + c];
        h2[(size_t)(r0 + r) * DO + c] = s;
    }
}

// ---------------- Agg2: out[n] = sum h2[src_e], d=40 ----------------
__global__ __launch_bounds__(256) void agg2_kernel(const float* __restrict__ h2,
                                                   const int* __restrict__ esrc,
                                                   const int* __restrict__ off,
                                                   float* __restrict__ out) {
    const int w = (blockIdx.x * 256 + threadIdx.x) >> 6;
    if (w >= NN) return;
    const int lane = threadIdx.x & 63;
    const int sub = lane / 10;
    const int c = (lane % 10) * 4;
    const int b = off[w], e = off[w + 1];
    float4 acc = make_float4(0.f, 0.f, 0.f, 0.f);
    if (sub < 6) {
        for (int j = b + sub; j < e; j += 6) {
            const int s = esrc[j];
            const float4 v = *(const float4*)(h2 + (size_t)s * DO + c);
            acc.x += v.x; acc.y += v.y; acc.z += v.z; acc.w += v.w;
        }
    }
    acc.x += __shfl(acc.x, lane + 30);
    acc.y += __shfl(acc.y, lane + 30);
    acc.z += __shfl(acc.z, lane + 30);
    acc.w += __shfl(acc.w, lane + 30);
    const float ax = acc.x + __shfl(acc.x, lane + 10) + __shfl(acc.x, lane + 20);
    const float ay = acc.y + __shfl(acc.y, lane + 10) + __shfl(acc.y, lane + 20);
    const float az = acc.z + __shfl(acc.z, lane + 10) + __shfl(acc.z, lane + 20);
    const float aw = acc.w + __shfl(acc.w, lane + 10) + __shfl(acc.w, lane + 20);
    if (lane < 10) {
        *(float4*)(out + (size_t)w * DO + c) = make_float4(ax, ay, az, aw);
    }
}

extern "C" void kernel_launch(void* const* d_in, const int* in_sizes, int n_in,
                              void* d_out, int out_size, void* d_ws, size_t ws_size,
                              hipStream_t stream) {
    const float* x  = (const float*)d_in[0];
    const int*   ei = (const int*)d_in[1];
    const float* W1 = (const float*)d_in[2];
    const float* W2 = (const float*)d_in[3];
    const int* src = ei;
    const int* dst = ei + NE;

    float* h1  = (float*)d_ws;                       // NN*128 f32 = 51.2 MB
    float* agg = h1 + (size_t)NN * DH;               // NN*128 f32 = 51.2 MB
    int2* epair = (int2*)agg;                        // 12.8 MB, aliases agg (dead before agg1)
    float* h2  = h1;                                 // aliases h1 (dead after agg1)
    int* ints  = (int*)(agg + (size_t)NN * DH);
    int* esrc   = ints;                              // NE
    int* off    = esrc + NE;                         // NN+1
    int* hist2d = off + NN + 1;                      // M2
    int* offs2d = hist2d + M2;                       // M2
    int* bsum   = offs2d + M2;                       // NBS
    int* boff   = bsum + NBS;                        // NBS

    float* out = (float*)d_out;

    gemm1_kernel<<<(NN + 63) / 64, 256, 0, stream>>>(x, W1, h1);
    bucket_hist_kernel<<<NB_BLK, 256, 0, stream>>>(dst, hist2d);
    spart_kernel<<<NBS, 256, 0, stream>>>(hist2d, bsum);
    sblock_kernel<<<1, 64, 0, stream>>>(bsum, boff);
    sfinal_kernel<<<NBS, 256, 0, stream>>>(hist2d, boff, offs2d);
    bucket_scatter_kernel<<<NB_BLK, 256, 0, stream>>>(src, dst, offs2d, epair);
    bucket_sort_kernel<<<NB, 256, 0, stream>>>(epair, offs2d, off, esrc);
    agg1_kernel<<<(NN * 64 + 255) / 256, 256, 0, stream>>>(h1, esrc, off, agg);
    gemm2_kernel<<<(NN + 7) / 8, 320, 0, stream>>>(agg, W2, h2);
    agg2_kernel<<<(NN * 64 + 255) / 256, 256, 0, stream>>>(h2, esrc, off, out);
}

// Round 5
// 513.691 us; speedup vs baseline: 7.7795x; 1.0550x over previous
//
#include <hip/hip_runtime.h>

constexpr int NN = 100000;   // nodes
constexpr int NE = 1600000;  // edges
constexpr int DI = 256, DH = 128, DO = 40;

// Bucket radix sort params
constexpr int NB = (NN + 255) >> 8;        // 391 buckets of 256 dst values
constexpr int NB_BLK = 128;                // blocks in hist/scatter passes
constexpr int CHUNK = NE / NB_BLK;         // 12500 edges per block (exact)
constexpr int M2 = NB * NB_BLK;            // 50048 hist entries
constexpr int NBS = (M2 + 1023) / 1024;    // 49 scan partials
constexpr int STAGE_CAP = 6144;            // bucket staging (avg load ~4092)

typedef __attribute__((ext_vector_type(8))) __bf16 bf16x8;
typedef __attribute__((ext_vector_type(4))) float f32x4;

// ---------------- GEMM1 (bf16 MFMA): h1[NN,128] = x[NN,256] @ W1[256,128] ----------------
// Block = 256 thr (4 waves) covers 128 rows; wave = 2 strips of 16 rows x 128 cols.
// W1 staged to LDS as bf16, transposed [n][k-local], K split in 2 halves of 128.
// Row stride 136 bf16 (272 B): 16B-aligned frags, bank-quads spread per 8-lane phase.
__device__ inline bf16x8 load_cvt_a(const float* __restrict__ p, bool ok) {
    bf16x8 r;
    if (ok) {
        const float4 v0 = *(const float4*)p;
        const float4 v1 = *(const float4*)(p + 4);
        r[0] = (__bf16)v0.x; r[1] = (__bf16)v0.y; r[2] = (__bf16)v0.z; r[3] = (__bf16)v0.w;
        r[4] = (__bf16)v1.x; r[5] = (__bf16)v1.y; r[6] = (__bf16)v1.z; r[7] = (__bf16)v1.w;
    } else {
        #pragma unroll
        for (int j = 0; j < 8; ++j) r[j] = (__bf16)0.f;
    }
    return r;
}

__global__ __launch_bounds__(256) void gemm1_kernel(const float* __restrict__ x,
                                                    const float* __restrict__ W,
                                                    float* __restrict__ h1) {
    __shared__ __bf16 Wt[128][136];   // [n][k-local], 34.8 KB
    const int t = threadIdx.x;
    const int wave = t >> 6, lane = t & 63;
    const int q = lane >> 4, m = lane & 15;
    const int row0 = blockIdx.x * 128 + wave * 32;
    const int r0 = row0 + m, r1 = row0 + 16 + m;
    const bool ok0 = r0 < NN, ok1 = r1 < NN;
    const float* xp0 = x + (size_t)r0 * DI;
    const float* xp1 = x + (size_t)r1 * DI;
    const int sn = t & 127;           // staging: column n
    const int kh = t >> 7;            // staging: k-half within stage

    f32x4 acc[2][8];
    #pragma unroll
    for (int s = 0; s < 2; ++s)
        #pragma unroll
        for (int nt = 0; nt < 8; ++nt)
            #pragma unroll
            for (int rr = 0; rr < 4; ++rr) acc[s][nt][rr] = 0.f;

    for (int half = 0; half < 2; ++half) {
        const int kbase = half * 128;
        #pragma unroll 4
        for (int kl = kh * 64; kl < kh * 64 + 64; ++kl)
            Wt[sn][kl] = (__bf16)W[(size_t)(kbase + kl) * DH + sn];
        __syncthreads();
        #pragma unroll
        for (int kt = 0; kt < 4; ++kt) {
            const int lo = kt * 32 + q * 8;        // local k of this frag
            const bf16x8 a0 = load_cvt_a(xp0 + kbase + lo, ok0);
            const bf16x8 a1 = load_cvt_a(xp1 + kbase + lo, ok1);
            #pragma unroll
            for (int nt = 0; nt < 8; ++nt) {
                const bf16x8 b = *(const bf16x8*)(&Wt[nt * 16 + m][lo]);
                acc[0][nt] = __builtin_amdgcn_mfma_f32_16x16x32_bf16(a0, b, acc[0][nt], 0, 0, 0);
                acc[1][nt] = __builtin_amdgcn_mfma_f32_16x16x32_bf16(a1, b, acc[1][nt], 0, 0, 0);
            }
        }
        __syncthreads();   // before restage
    }
    // store: D col = lane&15 (=m), row = q*4+reg
    #pragma unroll
    for (int s = 0; s < 2; ++s)
        #pragma unroll
        for (int reg = 0; reg < 4; ++reg) {
            const int r = row0 + s * 16 + q * 4 + reg;
            if (r < NN) {
                float* hp = h1 + (size_t)r * DH + m;
                #pragma unroll
                for (int nt = 0; nt < 8; ++nt) hp[nt * 16] = acc[s][nt][reg];
            }
        }
}

// ---------------- P1: per-block bucket histogram ----------------
__global__ __launch_bounds__(256) void bucket_hist_kernel(const int* __restrict__ dst,
                                                          int* __restrict__ hist2d) {
    __shared__ int h[NB];
    for (int i = threadIdx.x; i < NB; i += 256) h[i] = 0;
    __syncthreads();
    const int base = blockIdx.x * CHUNK;
    for (int i = threadIdx.x; i < CHUNK; i += 256)
        atomicAdd(&h[dst[base + i] >> 8], 1);
    __syncthreads();
    for (int i = threadIdx.x; i < NB; i += 256)
        hist2d[i * NB_BLK + blockIdx.x] = h[i];   // bucket-major
}

// ---------------- scan of hist2d (M2 entries) ----------------
__global__ __launch_bounds__(256) void spart_kernel(const int* __restrict__ in,
                                                    int* __restrict__ bsum) {
    __shared__ int red[256];
    const int idx = blockIdx.x * 1024 + threadIdx.x * 4;
    int s = 0;
    if (idx < M2) { const int4 v = *(const int4*)(in + idx); s = v.x + v.y + v.z + v.w; }
    red[threadIdx.x] = s;
    __syncthreads();
    #pragma unroll
    for (int d = 128; d > 0; d >>= 1) {
        if (threadIdx.x < d) red[threadIdx.x] += red[threadIdx.x + d];
        __syncthreads();
    }
    if (threadIdx.x == 0) bsum[blockIdx.x] = red[0];
}

__global__ __launch_bounds__(64) void sblock_kernel(const int* __restrict__ bsum,
                                                    int* __restrict__ boff) {
    __shared__ int part[64];
    const int t = threadIdx.x;
    const int v = (t < NBS) ? bsum[t] : 0;
    part[t] = v;
    __syncthreads();
    for (int d = 1; d < 64; d <<= 1) {
        const int u = (t >= d) ? part[t - d] : 0;
        __syncthreads();
        part[t] += u;
        __syncthreads();
    }
    if (t < NBS) boff[t] = part[t] - v;
}

__global__ __launch_bounds__(256) void sfinal_kernel(const int* __restrict__ in,
                                                     const int* __restrict__ boff,
                                                     int* __restrict__ out) {
    __shared__ int part[256];
    const int t = threadIdx.x;
    const int idx = blockIdx.x * 1024 + t * 4;
    int4 v = make_int4(0, 0, 0, 0);
    if (idx < M2) v = *(const int4*)(in + idx);
    const int s = v.x + v.y + v.z + v.w;
    part[t] = s;
    __syncthreads();
    for (int d = 1; d < 256; d <<= 1) {
        const int u = (t >= d) ? part[t - d] : 0;
        __syncthreads();
        part[t] += u;
        __syncthreads();
    }
    if (idx < M2) {
        const int base = boff[blockIdx.x] + part[t] - s;
        *(int4*)(out + idx) = make_int4(base, base + v.x, base + v.x + v.y,
                                        base + v.x + v.y + v.z);
    }
}

// ---------------- P3: scatter pairs into bucket partitions ----------------
__global__ __launch_bounds__(256) void bucket_scatter_kernel(const int* __restrict__ src,
                                                             const int* __restrict__ dst,
                                                             const int* __restrict__ offs2d,
                                                             int2* __restrict__ epair) {
    __shared__ int cur[NB];
    for (int i = threadIdx.x; i < NB; i += 256)
        cur[i] = offs2d[i * NB_BLK + blockIdx.x];
    __syncthreads();
    const int base = blockIdx.x * CHUNK;
    for (int i = threadIdx.x; i < CHUNK; i += 256) {
        const int d = dst[base + i], s = src[base + i];
        const int p = atomicAdd(&cur[d >> 8], 1);
        epair[p] = make_int2(s, d);
    }
}

// ---------------- P4: within-bucket counting sort; emits off[] and esrc ----------------
__global__ __launch_bounds__(256) void bucket_sort_kernel(const int2* __restrict__ epair,
                                                          const int* __restrict__ offs2d,
                                                          int* __restrict__ off,
                                                          int* __restrict__ esrc) {
    __shared__ int cnt[256];
    __shared__ int incl[256];
    __shared__ int cur[256];
    __shared__ int stage[STAGE_CAP];
    const int b = blockIdx.x;
    const int t = threadIdx.x;
    const int bstart = offs2d[b * NB_BLK];
    const int bend = (b + 1 < NB) ? offs2d[(b + 1) * NB_BLK] : NE;
    const int n = bend - bstart;
    cnt[t] = 0;
    __syncthreads();
    for (int i = t; i < n; i += 256)
        atomicAdd(&cnt[epair[bstart + i].y & 255], 1);
    __syncthreads();
    incl[t] = cnt[t];
    __syncthreads();
    for (int d = 1; d < 256; d <<= 1) {
        const int u = (t >= d) ? incl[t - d] : 0;
        __syncthreads();
        incl[t] += u;
        __syncthreads();
    }
    const int ex = incl[t] - cnt[t];   // exclusive prefix within bucket
    const int node = (b << 8) + t;
    if (node <= NN) off[node] = bstart + ex;   // node==NN -> off[NN]=NE
    cur[t] = ex;
    __syncthreads();
    const bool staged = (n <= STAGE_CAP);
    for (int i = t; i < n; i += 256) {
        const int2 pr = epair[bstart + i];
        const int p = atomicAdd(&cur[pr.y & 255], 1);
        if (staged) stage[p] = pr.x;
        else esrc[bstart + p] = pr.x;
    }
    __syncthreads();
    if (staged)
        for (int i = t; i < n; i += 256) esrc[bstart + i] = stage[i];
}

// ---------------- Agg1: agg[n] = relu(sum h1[src_e]), d=128 ----------------
__global__ __launch_bounds__(256) void agg1_kernel(const float* __restrict__ h1,
                                                   const int* __restrict__ esrc,
                                                   const int* __restrict__ off,
                                                   float* __restrict__ agg) {
    const int w = (blockIdx.x * 256 + threadIdx.x) >> 6;
    if (w >= NN) return;
    const int lane = threadIdx.x & 63;
    const int half = lane >> 5;
    const int c = (lane & 31) * 4;
    const int b = off[w], e = off[w + 1];
    float4 acc = make_float4(0.f, 0.f, 0.f, 0.f);
    for (int j = b + half; j < e; j += 2) {
        const int s = esrc[j];
        const float4 v = *(const float4*)(h1 + (size_t)s * DH + c);
        acc.x += v.x; acc.y += v.y; acc.z += v.z; acc.w += v.w;
    }
    acc.x += __shfl_xor(acc.x, 32);
    acc.y += __shfl_xor(acc.y, 32);
    acc.z += __shfl_xor(acc.z, 32);
    acc.w += __shfl_xor(acc.w, 32);
    if (half == 0) {
        *(float4*)(agg + (size_t)w * DH + c) =
            make_float4(fmaxf(acc.x, 0.f), fmaxf(acc.y, 0.f),
                        fmaxf(acc.z, 0.f), fmaxf(acc.w, 0.f));
    }
}

// ---------------- GEMM2: h2[NN,40] = agg[NN,128] @ W2[128,40] ----------------
__global__ __launch_bounds__(320) void gemm2_kernel(const float* __restrict__ agg,
                                                    const float* __restrict__ W2,
                                                    float* __restrict__ h2) {
    __shared__ float rows[8][DH];
    const int t = threadIdx.x;
    const int r0 = blockIdx.x * 8;
    for (int i = t; i < 8 * DH; i += 320) {
        const int r = i >> 7, c = i & 127;
        float v = 0.f;
        if (r0 + r < NN) v = agg[(size_t)(r0 + r) * DH + c];
        rows[r][c] = v;
    }
    __syncthreads();
    const int r = t / DO, c = t % DO;
    if (r0 + r < NN) {
        float s = 0.f;
        #pragma unroll 8
        for (int k = 0; k < DH; ++k) s += rows[r][k] * W2[k * DO + c];
        h2[(size_t)(r0 + r) * DO + c] = s;
    }
}

// ---------------- Agg2: out[n] = sum h2[src_e], d=40 ----------------
__global__ __launch_bounds__(256) void agg2_kernel(const float* __restrict__ h2,
                                                   const int* __restrict__ esrc,
                                                   const int* __restrict__ off,
                                                   float* __restrict__ out) {
    const int w = (blockIdx.x * 256 + threadIdx.x) >> 6;
    if (w >= NN) return;
    const int lane = threadIdx.x & 63;
    const int sub = lane / 10;
    const int c = (lane % 10) * 4;
    const int b = off[w], e = off[w + 1];
    float4 acc = make_float4(0.f, 0.f, 0.f, 0.f);
    if (sub < 6) {
        for (int j = b + sub; j < e; j += 6) {
            const int s = esrc[j];
            const float4 v = *(const float4*)(h2 + (size_t)s * DO + c);
            acc.x += v.x; acc.y += v.y; acc.z += v.z; acc.w += v.w;
        }
    }
    acc.x += __shfl(acc.x, lane + 30);
    acc.y += __shfl(acc.y, lane + 30);
    acc.z += __shfl(acc.z, lane + 30);
    acc.w += __shfl(acc.w, lane + 30);
    const float ax = acc.x + __shfl(acc.x, lane + 10) + __shfl(acc.x, lane + 20);
    const float ay = acc.y + __shfl(acc.y, lane + 10) + __shfl(acc.y, lane + 20);
    const float az = acc.z + __shfl(acc.z, lane + 10) + __shfl(acc.z, lane + 20);
    const float aw = acc.w + __shfl(acc.w, lane + 10) + __shfl(acc.w, lane + 20);
    if (lane < 10) {
        *(float4*)(out + (size_t)w * DO + c) = make_float4(ax, ay, az, aw);
    }
}

extern "C" void kernel_launch(void* const* d_in, const int* in_sizes, int n_in,
                              void* d_out, int out_size, void* d_ws, size_t ws_size,
                              hipStream_t stream) {
    const float* x  = (const float*)d_in[0];
    const int*   ei = (const int*)d_in[1];
    const float* W1 = (const float*)d_in[2];
    const float* W2 = (const float*)d_in[3];
    const int* src = ei;
    const int* dst = ei + NE;

    float* h1  = (float*)d_ws;                       // NN*128 f32 = 51.2 MB
    float* agg = h1 + (size_t)NN * DH;               // NN*128 f32 = 51.2 MB
    int2* epair = (int2*)agg;                        // 12.8 MB, aliases agg (dead before agg1)
    float* h2  = h1;                                 // aliases h1 (dead after agg1)
    int* ints  = (int*)(agg + (size_t)NN * DH);
    int* esrc   = ints;                              // NE
    int* off    = esrc + NE;                         // NN+1
    int* hist2d = off + NN + 1;                      // M2
    int* offs2d = hist2d + M2;                       // M2
    int* bsum   = offs2d + M2;                       // NBS
    int* boff   = bsum + NBS;                        // NBS

    float* out = (float*)d_out;

    gemm1_kernel<<<(NN + 127) / 128, 256, 0, stream>>>(x, W1, h1);
    bucket_hist_kernel<<<NB_BLK, 256, 0, stream>>>(dst, hist2d);
    spart_kernel<<<NBS, 256, 0, stream>>>(hist2d, bsum);
    sblock_kernel<<<1, 64, 0, stream>>>(bsum, boff);
    sfinal_kernel<<<NBS, 256, 0, stream>>>(hist2d, boff, offs2d);
    bucket_scatter_kernel<<<NB_BLK, 256, 0, stream>>>(src, dst, offs2d, epair);
    bucket_sort_kernel<<<NB, 256, 0, stream>>>(epair, offs2d, off, esrc);
    agg1_kernel<<<(NN * 64 + 255) / 256, 256, 0, stream>>>(h1, esrc, off, agg);
    gemm2_kernel<<<(NN + 7) / 8, 320, 0, stream>>>(agg, W2, h2);
    agg2_kernel<<<(NN * 64 + 255) / 256, 256, 0, stream>>>(h2, esrc, off, out);
}

// Round 6
// 480.912 us; speedup vs baseline: 8.3097x; 1.0682x over previous
//
#include <hip/hip_runtime.h>

constexpr int NN = 100000;   // nodes
constexpr int NE = 1600000;  // edges
constexpr int DI = 256, DH = 128, DO = 40;

// Bucket radix sort params
constexpr int NB = (NN + 255) >> 8;        // 391 buckets of 256 dst values
constexpr int NB_BLK = 128;                // blocks in hist/scatter passes
constexpr int CHUNK = NE / NB_BLK;         // 12500 edges per block (exact)
constexpr int M2 = NB * NB_BLK;            // 50048 hist entries
constexpr int NBS = (M2 + 1023) / 1024;    // 49 scan partials
constexpr int STAGE_CAP = 6144;            // bucket staging (avg load ~4092)

typedef __attribute__((ext_vector_type(8))) __bf16 bf16x8;
typedef __attribute__((ext_vector_type(4))) float f32x4;

__device__ inline float bf2f(__bf16 b) { return (float)b; }
__device__ inline float4 bf4_to_f4(ushort4 u) {
    return make_float4(__builtin_bit_cast(float, (unsigned)u.x << 16),
                       __builtin_bit_cast(float, (unsigned)u.y << 16),
                       __builtin_bit_cast(float, (unsigned)u.z << 16),
                       __builtin_bit_cast(float, (unsigned)u.w << 16));
}
__device__ inline unsigned short f2bf(float f) {
    return __builtin_bit_cast(unsigned short, (__bf16)f);   // RNE
}

// ---------------- GEMM1 (bf16 MFMA): h1[NN,128](bf16) = x[NN,256] @ W1[256,128] ----------
__device__ inline bf16x8 load_cvt_a(const float* __restrict__ p, bool ok) {
    bf16x8 r;
    if (ok) {
        const float4 v0 = *(const float4*)p;
        const float4 v1 = *(const float4*)(p + 4);
        r[0] = (__bf16)v0.x; r[1] = (__bf16)v0.y; r[2] = (__bf16)v0.z; r[3] = (__bf16)v0.w;
        r[4] = (__bf16)v1.x; r[5] = (__bf16)v1.y; r[6] = (__bf16)v1.z; r[7] = (__bf16)v1.w;
    } else {
        #pragma unroll
        for (int j = 0; j < 8; ++j) r[j] = (__bf16)0.f;
    }
    return r;
}

__global__ __launch_bounds__(256) void gemm1_kernel(const float* __restrict__ x,
                                                    const float* __restrict__ W,
                                                    __bf16* __restrict__ h1) {
    __shared__ __bf16 Wt[128][136];   // [n][k-local], 34.8 KB
    const int t = threadIdx.x;
    const int wave = t >> 6, lane = t & 63;
    const int q = lane >> 4, m = lane & 15;
    const int row0 = blockIdx.x * 128 + wave * 32;
    const int r0 = row0 + m, r1 = row0 + 16 + m;
    const bool ok0 = r0 < NN, ok1 = r1 < NN;
    const float* xp0 = x + (size_t)r0 * DI;
    const float* xp1 = x + (size_t)r1 * DI;
    const int sn = t & 127;
    const int kh = t >> 7;

    f32x4 acc[2][8];
    #pragma unroll
    for (int s = 0; s < 2; ++s)
        #pragma unroll
        for (int nt = 0; nt < 8; ++nt)
            #pragma unroll
            for (int rr = 0; rr < 4; ++rr) acc[s][nt][rr] = 0.f;

    for (int half = 0; half < 2; ++half) {
        const int kbase = half * 128;
        #pragma unroll 4
        for (int kl = kh * 64; kl < kh * 64 + 64; ++kl)
            Wt[sn][kl] = (__bf16)W[(size_t)(kbase + kl) * DH + sn];
        __syncthreads();
        #pragma unroll
        for (int kt = 0; kt < 4; ++kt) {
            const int lo = kt * 32 + q * 8;
            const bf16x8 a0 = load_cvt_a(xp0 + kbase + lo, ok0);
            const bf16x8 a1 = load_cvt_a(xp1 + kbase + lo, ok1);
            #pragma unroll
            for (int nt = 0; nt < 8; ++nt) {
                const bf16x8 b = *(const bf16x8*)(&Wt[nt * 16 + m][lo]);
                acc[0][nt] = __builtin_amdgcn_mfma_f32_16x16x32_bf16(a0, b, acc[0][nt], 0, 0, 0);
                acc[1][nt] = __builtin_amdgcn_mfma_f32_16x16x32_bf16(a1, b, acc[1][nt], 0, 0, 0);
            }
        }
        __syncthreads();
    }
    // store bf16: D col = lane&15 (=m), row = q*4+reg
    #pragma unroll
    for (int s = 0; s < 2; ++s)
        #pragma unroll
        for (int reg = 0; reg < 4; ++reg) {
            const int r = row0 + s * 16 + q * 4 + reg;
            if (r < NN) {
                __bf16* hp = h1 + (size_t)r * DH + m;
                #pragma unroll
                for (int nt = 0; nt < 8; ++nt) hp[nt * 16] = (__bf16)acc[s][nt][reg];
            }
        }
}

// ---------------- P1: per-block bucket histogram ----------------
__global__ __launch_bounds__(256) void bucket_hist_kernel(const int* __restrict__ dst,
                                                          int* __restrict__ hist2d) {
    __shared__ int h[NB];
    for (int i = threadIdx.x; i < NB; i += 256) h[i] = 0;
    __syncthreads();
    const int base = blockIdx.x * CHUNK;
    for (int i = threadIdx.x; i < CHUNK; i += 256)
        atomicAdd(&h[dst[base + i] >> 8], 1);
    __syncthreads();
    for (int i = threadIdx.x; i < NB; i += 256)
        hist2d[i * NB_BLK + blockIdx.x] = h[i];   // bucket-major
}

// ---------------- scan of hist2d (M2 entries) ----------------
__global__ __launch_bounds__(256) void spart_kernel(const int* __restrict__ in,
                                                    int* __restrict__ bsum) {
    __shared__ int red[256];
    const int idx = blockIdx.x * 1024 + threadIdx.x * 4;
    int s = 0;
    if (idx < M2) { const int4 v = *(const int4*)(in + idx); s = v.x + v.y + v.z + v.w; }
    red[threadIdx.x] = s;
    __syncthreads();
    #pragma unroll
    for (int d = 128; d > 0; d >>= 1) {
        if (threadIdx.x < d) red[threadIdx.x] += red[threadIdx.x + d];
        __syncthreads();
    }
    if (threadIdx.x == 0) bsum[blockIdx.x] = red[0];
}

__global__ __launch_bounds__(64) void sblock_kernel(const int* __restrict__ bsum,
                                                    int* __restrict__ boff) {
    __shared__ int part[64];
    const int t = threadIdx.x;
    const int v = (t < NBS) ? bsum[t] : 0;
    part[t] = v;
    __syncthreads();
    for (int d = 1; d < 64; d <<= 1) {
        const int u = (t >= d) ? part[t - d] : 0;
        __syncthreads();
        part[t] += u;
        __syncthreads();
    }
    if (t < NBS) boff[t] = part[t] - v;
}

__global__ __launch_bounds__(256) void sfinal_kernel(const int* __restrict__ in,
                                                     const int* __restrict__ boff,
                                                     int* __restrict__ out) {
    __shared__ int part[256];
    const int t = threadIdx.x;
    const int idx = blockIdx.x * 1024 + t * 4;
    int4 v = make_int4(0, 0, 0, 0);
    if (idx < M2) v = *(const int4*)(in + idx);
    const int s = v.x + v.y + v.z + v.w;
    part[t] = s;
    __syncthreads();
    for (int d = 1; d < 256; d <<= 1) {
        const int u = (t >= d) ? part[t - d] : 0;
        __syncthreads();
        part[t] += u;
        __syncthreads();
    }
    if (idx < M2) {
        const int base = boff[blockIdx.x] + part[t] - s;
        *(int4*)(out + idx) = make_int4(base, base + v.x, base + v.x + v.y,
                                        base + v.x + v.y + v.z);
    }
}

// ---------------- P3: scatter pairs into bucket partitions ----------------
__global__ __launch_bounds__(256) void bucket_scatter_kernel(const int* __restrict__ src,
                                                             const int* __restrict__ dst,
                                                             const int* __restrict__ offs2d,
                                                             int2* __restrict__ epair) {
    __shared__ int cur[NB];
    for (int i = threadIdx.x; i < NB; i += 256)
        cur[i] = offs2d[i * NB_BLK + blockIdx.x];
    __syncthreads();
    const int base = blockIdx.x * CHUNK;
    for (int i = threadIdx.x; i < CHUNK; i += 256) {
        const int d = dst[base + i], s = src[base + i];
        const int p = atomicAdd(&cur[d >> 8], 1);
        epair[p] = make_int2(s, d);
    }
}

// ---------------- P4: within-bucket counting sort; emits off[] and esrc ----------------
__global__ __launch_bounds__(256) void bucket_sort_kernel(const int2* __restrict__ epair,
                                                          const int* __restrict__ offs2d,
                                                          int* __restrict__ off,
                                                          int* __restrict__ esrc) {
    __shared__ int cnt[256];
    __shared__ int incl[256];
    __shared__ int cur[256];
    __shared__ int stage[STAGE_CAP];
    const int b = blockIdx.x;
    const int t = threadIdx.x;
    const int bstart = offs2d[b * NB_BLK];
    const int bend = (b + 1 < NB) ? offs2d[(b + 1) * NB_BLK] : NE;
    const int n = bend - bstart;
    cnt[t] = 0;
    __syncthreads();
    for (int i = t; i < n; i += 256)
        atomicAdd(&cnt[epair[bstart + i].y & 255], 1);
    __syncthreads();
    incl[t] = cnt[t];
    __syncthreads();
    for (int d = 1; d < 256; d <<= 1) {
        const int u = (t >= d) ? incl[t - d] : 0;
        __syncthreads();
        incl[t] += u;
        __syncthreads();
    }
    const int ex = incl[t] - cnt[t];   // exclusive prefix within bucket
    const int node = (b << 8) + t;
    if (node <= NN) off[node] = bstart + ex;   // node==NN -> off[NN]=NE
    cur[t] = ex;
    __syncthreads();
    const bool staged = (n <= STAGE_CAP);
    for (int i = t; i < n; i += 256) {
        const int2 pr = epair[bstart + i];
        const int p = atomicAdd(&cur[pr.y & 255], 1);
        if (staged) stage[p] = pr.x;
        else esrc[bstart + p] = pr.x;
    }
    __syncthreads();
    if (staged)
        for (int i = t; i < n; i += 256) esrc[bstart + i] = stage[i];
}

// ---------------- Agg1: agg[n](bf16) = relu(sum h1[src_e]), d=128 ----------------
// One wave per node; half-wave per edge (32 lanes x ushort4 = one 256B bf16 row),
// fp32 accumulate, shfl_xor(32) combine, bf16 store.
__global__ __launch_bounds__(256) void agg1_kernel(const __bf16* __restrict__ h1,
                                                   const int* __restrict__ esrc,
                                                   const int* __restrict__ off,
                                                   __bf16* __restrict__ agg) {
    const int w = (blockIdx.x * 256 + threadIdx.x) >> 6;
    if (w >= NN) return;
    const int lane = threadIdx.x & 63;
    const int half = lane >> 5;
    const int c = (lane & 31) * 4;
    const int b = off[w], e = off[w + 1];
    float4 acc = make_float4(0.f, 0.f, 0.f, 0.f);
    for (int j = b + half; j < e; j += 2) {
        const int s = esrc[j];
        const ushort4 u = *(const ushort4*)(h1 + (size_t)s * DH + c);
        const float4 v = bf4_to_f4(u);
        acc.x += v.x; acc.y += v.y; acc.z += v.z; acc.w += v.w;
    }
    acc.x += __shfl_xor(acc.x, 32);
    acc.y += __shfl_xor(acc.y, 32);
    acc.z += __shfl_xor(acc.z, 32);
    acc.w += __shfl_xor(acc.w, 32);
    if (half == 0) {
        ushort4 o;
        o.x = f2bf(fmaxf(acc.x, 0.f));
        o.y = f2bf(fmaxf(acc.y, 0.f));
        o.z = f2bf(fmaxf(acc.z, 0.f));
        o.w = f2bf(fmaxf(acc.w, 0.f));
        *(ushort4*)(agg + (size_t)w * DH + c) = o;
    }
}

// ---------------- GEMM2: h2[NN,40](bf16) = agg[NN,128](bf16) @ W2[128,40] ----------------
__global__ __launch_bounds__(320) void gemm2_kernel(const __bf16* __restrict__ agg,
                                                    const float* __restrict__ W2,
                                                    __bf16* __restrict__ h2) {
    __shared__ float rows[8][DH];
    const int t = threadIdx.x;
    const int r0 = blockIdx.x * 8;
    for (int i = t; i < 8 * DH; i += 320) {
        const int r = i >> 7, c = i & 127;
        float v = 0.f;
        if (r0 + r < NN) v = bf2f(agg[(size_t)(r0 + r) * DH + c]);
        rows[r][c] = v;
    }
    __syncthreads();
    const int r = t / DO, c = t % DO;
    if (r0 + r < NN) {
        float s = 0.f;
        #pragma unroll 8
        for (int k = 0; k < DH; ++k) s += rows[r][k] * W2[k * DO + c];
        h2[(size_t)(r0 + r) * DO + c] = (__bf16)s;
    }
}

// ---------------- Agg2: out[n](f32) = sum h2[src_e], d=40 ----------------
// One wave per node; 10 lanes x ushort4 = one 80B bf16 row, 6 edges per iteration,
// 2-step shuffle reduce over the 6 sub-accumulators.
__global__ __launch_bounds__(256) void agg2_kernel(const __bf16* __restrict__ h2,
                                                   const int* __restrict__ esrc,
                                                   const int* __restrict__ off,
                                                   float* __restrict__ out) {
    const int w = (blockIdx.x * 256 + threadIdx.x) >> 6;
    if (w >= NN) return;
    const int lane = threadIdx.x & 63;
    const int sub = lane / 10;          // 0..5 active, lanes 60..63 idle
    const int c = (lane % 10) * 4;
    const int b = off[w], e = off[w + 1];
    float4 acc = make_float4(0.f, 0.f, 0.f, 0.f);
    if (sub < 6) {
        for (int j = b + sub; j < e; j += 6) {
            const int s = esrc[j];
            const ushort4 u = *(const ushort4*)(h2 + (size_t)s * DO + c);
            const float4 v = bf4_to_f4(u);
            acc.x += v.x; acc.y += v.y; acc.z += v.z; acc.w += v.w;
        }
    }
    acc.x += __shfl(acc.x, lane + 30);
    acc.y += __shfl(acc.y, lane + 30);
    acc.z += __shfl(acc.z, lane + 30);
    acc.w += __shfl(acc.w, lane + 30);
    const float ax = acc.x + __shfl(acc.x, lane + 10) + __shfl(acc.x, lane + 20);
    const float ay = acc.y + __shfl(acc.y, lane + 10) + __shfl(acc.y, lane + 20);
    const float az = acc.z + __shfl(acc.z, lane + 10) + __shfl(acc.z, lane + 20);
    const float aw = acc.w + __shfl(acc.w, lane + 10) + __shfl(acc.w, lane + 20);
    if (lane < 10) {
        *(float4*)(out + (size_t)w * DO + c) = make_float4(ax, ay, az, aw);
    }
}

extern "C" void kernel_launch(void* const* d_in, const int* in_sizes, int n_in,
                              void* d_out, int out_size, void* d_ws, size_t ws_size,
                              hipStream_t stream) {
    const float* x  = (const float*)d_in[0];
    const int*   ei = (const int*)d_in[1];
    const float* W1 = (const float*)d_in[2];
    const float* W2 = (const float*)d_in[3];
    const int* src = ei;
    const int* dst = ei + NE;

    __bf16* h1  = (__bf16*)d_ws;                     // NN*128 bf16 = 25.6 MB
    __bf16* agg = h1 + (size_t)NN * DH;              // NN*128 bf16 = 25.6 MB
    __bf16* h2  = h1;                                // NN*40 bf16 (aliases h1; dead after agg1)
    int2* epair = (int2*)(agg + (size_t)NN * DH);    // NE int2 = 12.8 MB (8B-aligned: 51.2e6 %8==0)
    int* ints   = (int*)(epair + NE);
    int* esrc   = ints;                              // NE
    int* off    = esrc + NE;                         // NN+1
    int* hist2d = off + NN + 1;                      // M2
    int* offs2d = hist2d + M2;                       // M2
    int* bsum   = offs2d + M2;                       // NBS
    int* boff   = bsum + NBS;                        // NBS

    float* out = (float*)d_out;

    gemm1_kernel<<<(NN + 127) / 128, 256, 0, stream>>>(x, W1, h1);
    bucket_hist_kernel<<<NB_BLK, 256, 0, stream>>>(dst, hist2d);
    spart_kernel<<<NBS, 256, 0, stream>>>(hist2d, bsum);
    sblock_kernel<<<1, 64, 0, stream>>>(bsum, boff);
    sfinal_kernel<<<NBS, 256, 0, stream>>>(hist2d, boff, offs2d);
    bucket_scatter_kernel<<<NB_BLK, 256, 0, stream>>>(src, dst, offs2d, epair);
    bucket_sort_kernel<<<NB, 256, 0, stream>>>(epair, offs2d, off, esrc);
    agg1_kernel<<<(NN * 64 + 255) / 256, 256, 0, stream>>>(h1, esrc, off, agg);
    gemm2_kernel<<<(NN + 7) / 8, 320, 0, stream>>>(agg, W2, h2);
    agg2_kernel<<<(NN * 64 + 255) / 256, 256, 0, stream>>>(h2, esrc, off, out);
}

// Round 7
// 375.468 us; speedup vs baseline: 10.6434x; 1.2808x over previous
//
#include <hip/hip_runtime.h>

constexpr int NN = 100000;   // nodes
constexpr int NE = 1600000;  // edges
constexpr int DI = 256, DH = 128, DO = 40;

// Bucket radix sort params
constexpr int NB = (NN + 255) >> 8;        // 391 buckets of 256 dst values
constexpr int NB_BLK = 128;                // blocks in hist/scatter passes
constexpr int CHUNK = NE / NB_BLK;         // 12500 edges per block (exact)
constexpr int M2 = NB * NB_BLK;            // 50048 hist entries
constexpr int NBS = (M2 + 1023) / 1024;    // 49 scan partials
constexpr int STAGE_CAP = 6144;            // bucket staging (avg load ~4092)

typedef __attribute__((ext_vector_type(8))) __bf16 bf16x8;
typedef __attribute__((ext_vector_type(4))) float f32x4;

__device__ inline float bf2f(__bf16 b) { return (float)b; }
__device__ inline float4 bf4_to_f4(ushort4 u) {
    return make_float4(__builtin_bit_cast(float, (unsigned)u.x << 16),
                       __builtin_bit_cast(float, (unsigned)u.y << 16),
                       __builtin_bit_cast(float, (unsigned)u.z << 16),
                       __builtin_bit_cast(float, (unsigned)u.w << 16));
}
__device__ inline unsigned short f2bf(float f) {
    return __builtin_bit_cast(unsigned short, (__bf16)f);   // RNE
}
__device__ inline bf16x8 bf16x8_zero() {
    bf16x8 r;
    #pragma unroll
    for (int j = 0; j < 8; ++j) r[j] = (__bf16)0.f;
    return r;
}

// ---------------- GEMM1 (bf16 MFMA): h1[NN,128](bf16) = x[NN,256] @ W1[256,128] ----------
__device__ inline bf16x8 load_cvt_a(const float* __restrict__ p, bool ok) {
    if (!ok) return bf16x8_zero();
    bf16x8 r;
    const float4 v0 = *(const float4*)p;
    const float4 v1 = *(const float4*)(p + 4);
    r[0] = (__bf16)v0.x; r[1] = (__bf16)v0.y; r[2] = (__bf16)v0.z; r[3] = (__bf16)v0.w;
    r[4] = (__bf16)v1.x; r[5] = (__bf16)v1.y; r[6] = (__bf16)v1.z; r[7] = (__bf16)v1.w;
    return r;
}

__global__ __launch_bounds__(256) void gemm1_kernel(const float* __restrict__ x,
                                                    const float* __restrict__ W,
                                                    __bf16* __restrict__ h1) {
    __shared__ __bf16 Wt[128][136];   // [n][k-local], 34.8 KB
    const int t = threadIdx.x;
    const int wave = t >> 6, lane = t & 63;
    const int q = lane >> 4, m = lane & 15;
    const int row0 = blockIdx.x * 128 + wave * 32;
    const int r0 = row0 + m, r1 = row0 + 16 + m;
    const bool ok0 = r0 < NN, ok1 = r1 < NN;
    const float* xp0 = x + (size_t)r0 * DI;
    const float* xp1 = x + (size_t)r1 * DI;
    const int sn = t & 127;
    const int kh = t >> 7;

    f32x4 acc[2][8];
    #pragma unroll
    for (int s = 0; s < 2; ++s)
        #pragma unroll
        for (int nt = 0; nt < 8; ++nt)
            #pragma unroll
            for (int rr = 0; rr < 4; ++rr) acc[s][nt][rr] = 0.f;

    for (int half = 0; half < 2; ++half) {
        const int kbase = half * 128;
        #pragma unroll 4
        for (int kl = kh * 64; kl < kh * 64 + 64; ++kl)
            Wt[sn][kl] = (__bf16)W[(size_t)(kbase + kl) * DH + sn];
        __syncthreads();
        #pragma unroll
        for (int kt = 0; kt < 4; ++kt) {
            const int lo = kt * 32 + q * 8;
            const bf16x8 a0 = load_cvt_a(xp0 + kbase + lo, ok0);
            const bf16x8 a1 = load_cvt_a(xp1 + kbase + lo, ok1);
            #pragma unroll
            for (int nt = 0; nt < 8; ++nt) {
                const bf16x8 b = *(const bf16x8*)(&Wt[nt * 16 + m][lo]);
                acc[0][nt] = __builtin_amdgcn_mfma_f32_16x16x32_bf16(a0, b, acc[0][nt], 0, 0, 0);
                acc[1][nt] = __builtin_amdgcn_mfma_f32_16x16x32_bf16(a1, b, acc[1][nt], 0, 0, 0);
            }
        }
        __syncthreads();
    }
    #pragma unroll
    for (int s = 0; s < 2; ++s)
        #pragma unroll
        for (int reg = 0; reg < 4; ++reg) {
            const int r = row0 + s * 16 + q * 4 + reg;
            if (r < NN) {
                __bf16* hp = h1 + (size_t)r * DH + m;
                #pragma unroll
                for (int nt = 0; nt < 8; ++nt) hp[nt * 16] = (__bf16)acc[s][nt][reg];
            }
        }
}

// ---------------- P1: per-block bucket histogram ----------------
__global__ __launch_bounds__(256) void bucket_hist_kernel(const int* __restrict__ dst,
                                                          int* __restrict__ hist2d) {
    __shared__ int h[NB];
    for (int i = threadIdx.x; i < NB; i += 256) h[i] = 0;
    __syncthreads();
    const int base = blockIdx.x * CHUNK;
    for (int i = threadIdx.x; i < CHUNK; i += 256)
        atomicAdd(&h[dst[base + i] >> 8], 1);
    __syncthreads();
    for (int i = threadIdx.x; i < NB; i += 256)
        hist2d[i * NB_BLK + blockIdx.x] = h[i];   // bucket-major
}

// ---------------- scan of hist2d (M2 entries) ----------------
__global__ __launch_bounds__(256) void spart_kernel(const int* __restrict__ in,
                                                    int* __restrict__ bsum) {
    __shared__ int red[256];
    const int idx = blockIdx.x * 1024 + threadIdx.x * 4;
    int s = 0;
    if (idx < M2) { const int4 v = *(const int4*)(in + idx); s = v.x + v.y + v.z + v.w; }
    red[threadIdx.x] = s;
    __syncthreads();
    #pragma unroll
    for (int d = 128; d > 0; d >>= 1) {
        if (threadIdx.x < d) red[threadIdx.x] += red[threadIdx.x + d];
        __syncthreads();
    }
    if (threadIdx.x == 0) bsum[blockIdx.x] = red[0];
}

__global__ __launch_bounds__(64) void sblock_kernel(const int* __restrict__ bsum,
                                                    int* __restrict__ boff) {
    __shared__ int part[64];
    const int t = threadIdx.x;
    const int v = (t < NBS) ? bsum[t] : 0;
    part[t] = v;
    __syncthreads();
    for (int d = 1; d < 64; d <<= 1) {
        const int u = (t >= d) ? part[t - d] : 0;
        __syncthreads();
        part[t] += u;
        __syncthreads();
    }
    if (t < NBS) boff[t] = part[t] - v;
}

__global__ __launch_bounds__(256) void sfinal_kernel(const int* __restrict__ in,
                                                     const int* __restrict__ boff,
                                                     int* __restrict__ out) {
    __shared__ int part[256];
    const int t = threadIdx.x;
    const int idx = blockIdx.x * 1024 + t * 4;
    int4 v = make_int4(0, 0, 0, 0);
    if (idx < M2) v = *(const int4*)(in + idx);
    const int s = v.x + v.y + v.z + v.w;
    part[t] = s;
    __syncthreads();
    for (int d = 1; d < 256; d <<= 1) {
        const int u = (t >= d) ? part[t - d] : 0;
        __syncthreads();
        part[t] += u;
        __syncthreads();
    }
    if (idx < M2) {
        const int base = boff[blockIdx.x] + part[t] - s;
        *(int4*)(out + idx) = make_int4(base, base + v.x, base + v.x + v.y,
                                        base + v.x + v.y + v.z);
    }
}

// ---------------- P3: scatter pairs into bucket partitions ----------------
__global__ __launch_bounds__(256) void bucket_scatter_kernel(const int* __restrict__ src,
                                                             const int* __restrict__ dst,
                                                             const int* __restrict__ offs2d,
                                                             int2* __restrict__ epair) {
    __shared__ int cur[NB];
    for (int i = threadIdx.x; i < NB; i += 256)
        cur[i] = offs2d[i * NB_BLK + blockIdx.x];
    __syncthreads();
    const int base = blockIdx.x * CHUNK;
    for (int i = threadIdx.x; i < CHUNK; i += 256) {
        const int d = dst[base + i], s = src[base + i];
        const int p = atomicAdd(&cur[d >> 8], 1);
        epair[p] = make_int2(s, d);
    }
}

// ---------------- P4: within-bucket counting sort; emits off[] and esrc ----------------
__global__ __launch_bounds__(256) void bucket_sort_kernel(const int2* __restrict__ epair,
                                                          const int* __restrict__ offs2d,
                                                          int* __restrict__ off,
                                                          int* __restrict__ esrc) {
    __shared__ int cnt[256];
    __shared__ int incl[256];
    __shared__ int cur[256];
    __shared__ int stage[STAGE_CAP];
    const int b = blockIdx.x;
    const int t = threadIdx.x;
    const int bstart = offs2d[b * NB_BLK];
    const int bend = (b + 1 < NB) ? offs2d[(b + 1) * NB_BLK] : NE;
    const int n = bend - bstart;
    cnt[t] = 0;
    __syncthreads();
    for (int i = t; i < n; i += 256)
        atomicAdd(&cnt[epair[bstart + i].y & 255], 1);
    __syncthreads();
    incl[t] = cnt[t];
    __syncthreads();
    for (int d = 1; d < 256; d <<= 1) {
        const int u = (t >= d) ? incl[t - d] : 0;
        __syncthreads();
        incl[t] += u;
        __syncthreads();
    }
    const int ex = incl[t] - cnt[t];   // exclusive prefix within bucket
    const int node = (b << 8) + t;
    if (node <= NN) off[node] = bstart + ex;   // node==NN -> off[NN]=NE
    cur[t] = ex;
    __syncthreads();
    const bool staged = (n <= STAGE_CAP);
    for (int i = t; i < n; i += 256) {
        const int2 pr = epair[bstart + i];
        const int p = atomicAdd(&cur[pr.y & 255], 1);
        if (staged) stage[p] = pr.x;
        else esrc[bstart + p] = pr.x;
    }
    __syncthreads();
    if (staged)
        for (int i = t; i < n; i += 256) esrc[bstart + i] = stage[i];
}

// ---------------- Agg1: agg[n](bf16) = relu(sum h1[src_e]), d=128 ----------------
// Half-wave per edge (32 lanes x ushort4 = one 256B row); unroll 4 -> 8 loads in flight.
__global__ __launch_bounds__(256) void agg1_kernel(const __bf16* __restrict__ h1,
                                                   const int* __restrict__ esrc,
                                                   const int* __restrict__ off,
                                                   __bf16* __restrict__ agg) {
    const int w = (blockIdx.x * 256 + threadIdx.x) >> 6;
    if (w >= NN) return;
    const int lane = threadIdx.x & 63;
    const int half = lane >> 5;
    const int c = (lane & 31) * 4;
    const int b = off[w], e = off[w + 1];
    float4 a0 = make_float4(0.f, 0.f, 0.f, 0.f);
    float4 a1 = a0, a2 = a0, a3 = a0;
    int j = b + half;
    for (; j + 6 < e; j += 8) {
        const int s0 = esrc[j], s1 = esrc[j + 2], s2 = esrc[j + 4], s3 = esrc[j + 6];
        const float4 v0 = bf4_to_f4(*(const ushort4*)(h1 + (size_t)s0 * DH + c));
        const float4 v1 = bf4_to_f4(*(const ushort4*)(h1 + (size_t)s1 * DH + c));
        const float4 v2 = bf4_to_f4(*(const ushort4*)(h1 + (size_t)s2 * DH + c));
        const float4 v3 = bf4_to_f4(*(const ushort4*)(h1 + (size_t)s3 * DH + c));
        a0.x += v0.x; a0.y += v0.y; a0.z += v0.z; a0.w += v0.w;
        a1.x += v1.x; a1.y += v1.y; a1.z += v1.z; a1.w += v1.w;
        a2.x += v2.x; a2.y += v2.y; a2.z += v2.z; a2.w += v2.w;
        a3.x += v3.x; a3.y += v3.y; a3.z += v3.z; a3.w += v3.w;
    }
    for (; j < e; j += 2) {
        const int s = esrc[j];
        const float4 v = bf4_to_f4(*(const ushort4*)(h1 + (size_t)s * DH + c));
        a0.x += v.x; a0.y += v.y; a0.z += v.z; a0.w += v.w;
    }
    float4 acc = make_float4(a0.x + a1.x + a2.x + a3.x,
                             a0.y + a1.y + a2.y + a3.y,
                             a0.z + a1.z + a2.z + a3.z,
                             a0.w + a1.w + a2.w + a3.w);
    acc.x += __shfl_xor(acc.x, 32);
    acc.y += __shfl_xor(acc.y, 32);
    acc.z += __shfl_xor(acc.z, 32);
    acc.w += __shfl_xor(acc.w, 32);
    if (half == 0) {
        ushort4 o;
        o.x = f2bf(fmaxf(acc.x, 0.f));
        o.y = f2bf(fmaxf(acc.y, 0.f));
        o.z = f2bf(fmaxf(acc.z, 0.f));
        o.w = f2bf(fmaxf(acc.w, 0.f));
        *(ushort4*)(agg + (size_t)w * DH + c) = o;
    }
}

// ---------------- GEMM2 (bf16 MFMA): h2[NN,40](bf16) = agg[NN,128](bf16) @ W2[128,40] ----
// 256 thr (4 waves), 64 rows/block (16 per wave). N padded to 48 (3 n-tiles of 16).
__global__ __launch_bounds__(256) void gemm2_kernel(const __bf16* __restrict__ agg,
                                                    const float* __restrict__ W2,
                                                    __bf16* __restrict__ h2) {
    __shared__ __bf16 Wt2[48][136];   // [n][k], 13 KB
    const int t = threadIdx.x;
    const int wave = t >> 6, lane = t & 63;
    const int q = lane >> 4, m = lane & 15;
    const int row0 = blockIdx.x * 64 + wave * 16;
    for (int i = t; i < DH * DO; i += 256) {       // W2[k][n] f32 -> Wt2[n][k] bf16
        const int k = i / DO, n = i % DO;
        Wt2[n][k] = (__bf16)W2[i];
    }
    for (int i = t; i < 8 * DH; i += 256)          // zero-pad n in [40,48)
        Wt2[DO + (i >> 7)][i & 127] = (__bf16)0.f;
    __syncthreads();
    const int r = row0 + m;
    const bool okA = r < NN;
    const __bf16* ap = agg + (size_t)r * DH;
    f32x4 acc[3];
    #pragma unroll
    for (int nt = 0; nt < 3; ++nt)
        #pragma unroll
        for (int rr = 0; rr < 4; ++rr) acc[nt][rr] = 0.f;
    #pragma unroll
    for (int ks = 0; ks < 4; ++ks) {
        const int k0 = ks * 32 + q * 8;
        const bf16x8 a = okA ? *(const bf16x8*)(ap + k0) : bf16x8_zero();
        #pragma unroll
        for (int nt = 0; nt < 3; ++nt) {
            const bf16x8 b = *(const bf16x8*)(&Wt2[nt * 16 + m][k0]);
            acc[nt] = __builtin_amdgcn_mfma_f32_16x16x32_bf16(a, b, acc[nt], 0, 0, 0);
        }
    }
    #pragma unroll
    for (int reg = 0; reg < 4; ++reg) {
        const int rr = row0 + q * 4 + reg;
        if (rr < NN) {
            #pragma unroll
            for (int nt = 0; nt < 3; ++nt) {
                const int cc = nt * 16 + m;
                if (cc < DO) h2[(size_t)rr * DO + cc] = (__bf16)acc[nt][reg];
            }
        }
    }
}

// ---------------- Agg2: out[n](f32) = sum h2[src_e], d=40 ----------------
// 10 lanes x ushort4 = one 80B row, 6 edges/iter, unroll 3 -> 18 loads in flight.
__global__ __launch_bounds__(256) void agg2_kernel(const __bf16* __restrict__ h2,
                                                   const int* __restrict__ esrc,
                                                   const int* __restrict__ off,
                                                   float* __restrict__ out) {
    const int w = (blockIdx.x * 256 + threadIdx.x) >> 6;
    if (w >= NN) return;
    const int lane = threadIdx.x & 63;
    const int sub = lane / 10;          // 0..5 active, lanes 60..63 idle
    const int c = (lane % 10) * 4;
    const int b = off[w], e = off[w + 1];
    float4 a0 = make_float4(0.f, 0.f, 0.f, 0.f);
    float4 a1 = a0, a2 = a0;
    if (sub < 6) {
        int j = b + sub;
        for (; j + 12 < e; j += 18) {
            const int s0 = esrc[j], s1 = esrc[j + 6], s2 = esrc[j + 12];
            const float4 v0 = bf4_to_f4(*(const ushort4*)(h2 + (size_t)s0 * DO + c));
            const float4 v1 = bf4_to_f4(*(const ushort4*)(h2 + (size_t)s1 * DO + c));
            const float4 v2 = bf4_to_f4(*(const ushort4*)(h2 + (size_t)s2 * DO + c));
            a0.x += v0.x; a0.y += v0.y; a0.z += v0.z; a0.w += v0.w;
            a1.x += v1.x; a1.y += v1.y; a1.z += v1.z; a1.w += v1.w;
            a2.x += v2.x; a2.y += v2.y; a2.z += v2.z; a2.w += v2.w;
        }
        for (; j < e; j += 6) {
            const int s = esrc[j];
            const float4 v = bf4_to_f4(*(const ushort4*)(h2 + (size_t)s * DO + c));
            a0.x += v.x; a0.y += v.y; a0.z += v.z; a0.w += v.w;
        }
    }
    float4 acc = make_float4(a0.x + a1.x + a2.x, a0.y + a1.y + a2.y,
                             a0.z + a1.z + a2.z, a0.w + a1.w + a2.w);
    acc.x += __shfl(acc.x, lane + 30);
    acc.y += __shfl(acc.y, lane + 30);
    acc.z += __shfl(acc.z, lane + 30);
    acc.w += __shfl(acc.w, lane + 30);
    const float ax = acc.x + __shfl(acc.x, lane + 10) + __shfl(acc.x, lane + 20);
    const float ay = acc.y + __shfl(acc.y, lane + 10) + __shfl(acc.y, lane + 20);
    const float az = acc.z + __shfl(acc.z, lane + 10) + __shfl(acc.z, lane + 20);
    const float aw = acc.w + __shfl(acc.w, lane + 10) + __shfl(acc.w, lane + 20);
    if (lane < 10) {
        *(float4*)(out + (size_t)w * DO + c) = make_float4(ax, ay, az, aw);
    }
}

extern "C" void kernel_launch(void* const* d_in, const int* in_sizes, int n_in,
                              void* d_out, int out_size, void* d_ws, size_t ws_size,
                              hipStream_t stream) {
    const float* x  = (const float*)d_in[0];
    const int*   ei = (const int*)d_in[1];
    const float* W1 = (const float*)d_in[2];
    const float* W2 = (const float*)d_in[3];
    const int* src = ei;
    const int* dst = ei + NE;

    __bf16* h1  = (__bf16*)d_ws;                     // NN*128 bf16 = 25.6 MB
    __bf16* agg = h1 + (size_t)NN * DH;              // NN*128 bf16 = 25.6 MB
    __bf16* h2  = h1;                                // NN*40 bf16 (aliases h1; dead after agg1)
    int2* epair = (int2*)(agg + (size_t)NN * DH);    // NE int2 = 12.8 MB
    int* ints   = (int*)(epair + NE);
    int* esrc   = ints;                              // NE
    int* off    = esrc + NE;                         // NN+1
    int* hist2d = off + NN + 1;                      // M2
    int* offs2d = hist2d + M2;                       // M2
    int* bsum   = offs2d + M2;                       // NBS
    int* boff   = bsum + NBS;                        // NBS

    float* out = (float*)d_out;

    gemm1_kernel<<<(NN + 127) / 128, 256, 0, stream>>>(x, W1, h1);
    bucket_hist_kernel<<<NB_BLK, 256, 0, stream>>>(dst, hist2d);
    spart_kernel<<<NBS, 256, 0, stream>>>(hist2d, bsum);
    sblock_kernel<<<1, 64, 0, stream>>>(bsum, boff);
    sfinal_kernel<<<NBS, 256, 0, stream>>>(hist2d, boff, offs2d);
    bucket_scatter_kernel<<<NB_BLK, 256, 0, stream>>>(src, dst, offs2d, epair);
    bucket_sort_kernel<<<NB, 256, 0, stream>>>(epair, offs2d, off, esrc);
    agg1_kernel<<<(NN * 64 + 255) / 256, 256, 0, stream>>>(h1, esrc, off, agg);
    gemm2_kernel<<<(NN + 63) / 64, 256, 0, stream>>>(agg, W2, h2);
    agg2_kernel<<<(NN * 64 + 255) / 256, 256, 0, stream>>>(h2, esrc, off, out);
}

// Round 8
// 366.674 us; speedup vs baseline: 10.8987x; 1.0240x over previous
//
#include <hip/hip_runtime.h>

constexpr int NN = 100000;   // nodes
constexpr int NE = 1600000;  // edges
constexpr int DI = 256, DH = 128, DO = 40;

// Bucket radix sort params
constexpr int NB = (NN + 255) >> 8;        // 391 buckets of 256 dst values
constexpr int NB_BLK = 128;                // blocks in hist/scatter passes
constexpr int CHUNK = NE / NB_BLK;         // 12500 edges per block (exact)
constexpr int M2 = NB * NB_BLK;            // 50048 hist entries
constexpr int NBS = (M2 + 1023) / 1024;    // 49 scan partials
constexpr int STAGE_CAP = 6144;            // bucket staging (avg load ~4092)

typedef __attribute__((ext_vector_type(8))) __bf16 bf16x8;
typedef __attribute__((ext_vector_type(4))) float f32x4;

__device__ inline float bf2f(__bf16 b) { return (float)b; }
__device__ inline float4 bf4_to_f4(ushort4 u) {
    return make_float4(__builtin_bit_cast(float, (unsigned)u.x << 16),
                       __builtin_bit_cast(float, (unsigned)u.y << 16),
                       __builtin_bit_cast(float, (unsigned)u.z << 16),
                       __builtin_bit_cast(float, (unsigned)u.w << 16));
}
__device__ inline unsigned short f2bf(float f) {
    return __builtin_bit_cast(unsigned short, (__bf16)f);   // RNE
}
__device__ inline bf16x8 bf16x8_zero() {
    bf16x8 r;
    #pragma unroll
    for (int j = 0; j < 8; ++j) r[j] = (__bf16)0.f;
    return r;
}
__device__ inline bf16x8 load_cvt_a(const float* __restrict__ p, bool ok) {
    if (!ok) return bf16x8_zero();
    bf16x8 r;
    const float4 v0 = *(const float4*)p;
    const float4 v1 = *(const float4*)(p + 4);
    r[0] = (__bf16)v0.x; r[1] = (__bf16)v0.y; r[2] = (__bf16)v0.z; r[3] = (__bf16)v0.w;
    r[4] = (__bf16)v1.x; r[5] = (__bf16)v1.y; r[6] = (__bf16)v1.z; r[7] = (__bf16)v1.w;
    return r;
}

// ---------------- W1 pack: W1[256,128] f32 -> Wf in MFMA B-frag order ----------------
// Wf index = ((kt*8 + nt)*64 + lane)*8 + j  where lane=(q,m): value = W1[k][n],
// k = kt*32 + q*8 + j, n = nt*16 + m.  (64 KB, L2-resident, 1 KB coalesced per wave.)
__global__ __launch_bounds__(256) void w1pack_kernel(const float* __restrict__ W,
                                                     __bf16* __restrict__ Wf) {
    const int i = blockIdx.x * 256 + threadIdx.x;   // 32768 total
    const int j = i & 7;
    const int lane = (i >> 3) & 63;
    const int nt = (i >> 9) & 7;
    const int kt = i >> 12;
    const int k = kt * 32 + (lane >> 4) * 8 + j;
    const int n = nt * 16 + (lane & 15);
    Wf[i] = (__bf16)W[(size_t)k * DH + n];
}

// ---------------- GEMM1 (bf16 MFMA, no LDS, no barriers) ----------------
// h1[NN,128](bf16) = x[NN,256] @ W1. One wave owns 16 rows; all 8 A-frags
// preloaded (256 B/lane), B-frags stream from packed Wf (L2-hot).
__global__ __launch_bounds__(256) void gemm1_kernel(const float* __restrict__ x,
                                                    const __bf16* __restrict__ Wf,
                                                    __bf16* __restrict__ h1) {
    const int t = threadIdx.x;
    const int wave = t >> 6, lane = t & 63;
    const int q = lane >> 4, m = lane & 15;
    const int row0 = blockIdx.x * 64 + wave * 16;
    const int r = row0 + m;
    const bool ok = r < NN;
    const float* xp = x + (size_t)r * DI;

    bf16x8 a[8];
    #pragma unroll
    for (int kt = 0; kt < 8; ++kt)
        a[kt] = load_cvt_a(xp + kt * 32 + q * 8, ok);

    f32x4 acc[8];
    #pragma unroll
    for (int nt = 0; nt < 8; ++nt)
        #pragma unroll
        for (int rr = 0; rr < 4; ++rr) acc[nt][rr] = 0.f;

    const bf16x8* wf = (const bf16x8*)Wf;
    #pragma unroll
    for (int kt = 0; kt < 8; ++kt) {
        #pragma unroll
        for (int nt = 0; nt < 8; ++nt) {
            const bf16x8 b = wf[(kt * 8 + nt) * 64 + lane];
            acc[nt] = __builtin_amdgcn_mfma_f32_16x16x32_bf16(a[kt], b, acc[nt], 0, 0, 0);
        }
    }
    // store: D col = m (n), row = q*4+reg
    #pragma unroll
    for (int reg = 0; reg < 4; ++reg) {
        const int rr = row0 + q * 4 + reg;
        if (rr < NN) {
            __bf16* hp = h1 + (size_t)rr * DH + m;
            #pragma unroll
            for (int nt = 0; nt < 8; ++nt) hp[nt * 16] = (__bf16)acc[nt][reg];
        }
    }
}

// ---------------- P1: per-block bucket histogram ----------------
__global__ __launch_bounds__(256) void bucket_hist_kernel(const int* __restrict__ dst,
                                                          int* __restrict__ hist2d) {
    __shared__ int h[NB];
    for (int i = threadIdx.x; i < NB; i += 256) h[i] = 0;
    __syncthreads();
    const int base = blockIdx.x * CHUNK;
    for (int i = threadIdx.x; i < CHUNK; i += 256)
        atomicAdd(&h[dst[base + i] >> 8], 1);
    __syncthreads();
    for (int i = threadIdx.x; i < NB; i += 256)
        hist2d[i * NB_BLK + blockIdx.x] = h[i];   // bucket-major
}

// ---------------- scan of hist2d (M2 entries) ----------------
__global__ __launch_bounds__(256) void spart_kernel(const int* __restrict__ in,
                                                    int* __restrict__ bsum) {
    __shared__ int red[256];
    const int idx = blockIdx.x * 1024 + threadIdx.x * 4;
    int s = 0;
    if (idx < M2) { const int4 v = *(const int4*)(in + idx); s = v.x + v.y + v.z + v.w; }
    red[threadIdx.x] = s;
    __syncthreads();
    #pragma unroll
    for (int d = 128; d > 0; d >>= 1) {
        if (threadIdx.x < d) red[threadIdx.x] += red[threadIdx.x + d];
        __syncthreads();
    }
    if (threadIdx.x == 0) bsum[blockIdx.x] = red[0];
}

__global__ __launch_bounds__(64) void sblock_kernel(const int* __restrict__ bsum,
                                                    int* __restrict__ boff) {
    __shared__ int part[64];
    const int t = threadIdx.x;
    const int v = (t < NBS) ? bsum[t] : 0;
    part[t] = v;
    __syncthreads();
    for (int d = 1; d < 64; d <<= 1) {
        const int u = (t >= d) ? part[t - d] : 0;
        __syncthreads();
        part[t] += u;
        __syncthreads();
    }
    if (t < NBS) boff[t] = part[t] - v;
}

__global__ __launch_bounds__(256) void sfinal_kernel(const int* __restrict__ in,
                                                     const int* __restrict__ boff,
                                                     int* __restrict__ out) {
    __shared__ int part[256];
    const int t = threadIdx.x;
    const int idx = blockIdx.x * 1024 + t * 4;
    int4 v = make_int4(0, 0, 0, 0);
    if (idx < M2) v = *(const int4*)(in + idx);
    const int s = v.x + v.y + v.z + v.w;
    part[t] = s;
    __syncthreads();
    for (int d = 1; d < 256; d <<= 1) {
        const int u = (t >= d) ? part[t - d] : 0;
        __syncthreads();
        part[t] += u;
        __syncthreads();
    }
    if (idx < M2) {
        const int base = boff[blockIdx.x] + part[t] - s;
        *(int4*)(out + idx) = make_int4(base, base + v.x, base + v.x + v.y,
                                        base + v.x + v.y + v.z);
    }
}

// ---------------- P3: scatter packed (src | dstbyte<<24) into bucket partitions -------
// src < 2^24 so it fits in 24 bits; P4 only needs dst&255.
__global__ __launch_bounds__(256) void bucket_scatter_kernel(const int* __restrict__ src,
                                                             const int* __restrict__ dst,
                                                             const int* __restrict__ offs2d,
                                                             unsigned* __restrict__ epack) {
    __shared__ int cur[NB];
    for (int i = threadIdx.x; i < NB; i += 256)
        cur[i] = offs2d[i * NB_BLK + blockIdx.x];
    __syncthreads();
    const int base = blockIdx.x * CHUNK;
    for (int i = threadIdx.x; i < CHUNK; i += 256) {
        const int d = dst[base + i], s = src[base + i];
        const int p = atomicAdd(&cur[d >> 8], 1);
        epack[p] = (unsigned)s | ((unsigned)(d & 255) << 24);
    }
}

// ---------------- P4: within-bucket counting sort; emits off[] and esrc ----------------
__global__ __launch_bounds__(256) void bucket_sort_kernel(const unsigned* __restrict__ epack,
                                                          const int* __restrict__ offs2d,
                                                          int* __restrict__ off,
                                                          int* __restrict__ esrc) {
    __shared__ int cnt[256];
    __shared__ int incl[256];
    __shared__ int cur[256];
    __shared__ int stage[STAGE_CAP];
    const int b = blockIdx.x;
    const int t = threadIdx.x;
    const int bstart = offs2d[b * NB_BLK];
    const int bend = (b + 1 < NB) ? offs2d[(b + 1) * NB_BLK] : NE;
    const int n = bend - bstart;
    cnt[t] = 0;
    __syncthreads();
    for (int i = t; i < n; i += 256)
        atomicAdd(&cnt[epack[bstart + i] >> 24], 1);
    __syncthreads();
    incl[t] = cnt[t];
    __syncthreads();
    for (int d = 1; d < 256; d <<= 1) {
        const int u = (t >= d) ? incl[t - d] : 0;
        __syncthreads();
        incl[t] += u;
        __syncthreads();
    }
    const int ex = incl[t] - cnt[t];   // exclusive prefix within bucket
    const int node = (b << 8) + t;
    if (node <= NN) off[node] = bstart + ex;   // node==NN -> off[NN]=NE
    cur[t] = ex;
    __syncthreads();
    const bool staged = (n <= STAGE_CAP);
    for (int i = t; i < n; i += 256) {
        const unsigned pk = epack[bstart + i];
        const int p = atomicAdd(&cur[pk >> 24], 1);
        const int s = (int)(pk & 0xFFFFFFu);
        if (staged) stage[p] = s;
        else esrc[bstart + p] = s;
    }
    __syncthreads();
    if (staged)
        for (int i = t; i < n; i += 256) esrc[bstart + i] = stage[i];
}

// ---------------- Agg1: agg[n](bf16) = relu(sum h1[src_e]), d=128 ----------------
// Half-wave per edge (32 lanes x ushort4 = one 256B row); unroll 4 -> 8 loads in flight.
__global__ __launch_bounds__(256) void agg1_kernel(const __bf16* __restrict__ h1,
                                                   const int* __restrict__ esrc,
                                                   const int* __restrict__ off,
                                                   __bf16* __restrict__ agg) {
    const int w = (blockIdx.x * 256 + threadIdx.x) >> 6;
    if (w >= NN) return;
    const int lane = threadIdx.x & 63;
    const int half = lane >> 5;
    const int c = (lane & 31) * 4;
    const int b = off[w], e = off[w + 1];
    float4 a0 = make_float4(0.f, 0.f, 0.f, 0.f);
    float4 a1 = a0, a2 = a0, a3 = a0;
    int j = b + half;
    for (; j + 6 < e; j += 8) {
        const int s0 = esrc[j], s1 = esrc[j + 2], s2 = esrc[j + 4], s3 = esrc[j + 6];
        const float4 v0 = bf4_to_f4(*(const ushort4*)(h1 + (size_t)s0 * DH + c));
        const float4 v1 = bf4_to_f4(*(const ushort4*)(h1 + (size_t)s1 * DH + c));
        const float4 v2 = bf4_to_f4(*(const ushort4*)(h1 + (size_t)s2 * DH + c));
        const float4 v3 = bf4_to_f4(*(const ushort4*)(h1 + (size_t)s3 * DH + c));
        a0.x += v0.x; a0.y += v0.y; a0.z += v0.z; a0.w += v0.w;
        a1.x += v1.x; a1.y += v1.y; a1.z += v1.z; a1.w += v1.w;
        a2.x += v2.x; a2.y += v2.y; a2.z += v2.z; a2.w += v2.w;
        a3.x += v3.x; a3.y += v3.y; a3.z += v3.z; a3.w += v3.w;
    }
    for (; j < e; j += 2) {
        const int s = esrc[j];
        const float4 v = bf4_to_f4(*(const ushort4*)(h1 + (size_t)s * DH + c));
        a0.x += v.x; a0.y += v.y; a0.z += v.z; a0.w += v.w;
    }
    float4 acc = make_float4(a0.x + a1.x + a2.x + a3.x,
                             a0.y + a1.y + a2.y + a3.y,
                             a0.z + a1.z + a2.z + a3.z,
                             a0.w + a1.w + a2.w + a3.w);
    acc.x += __shfl_xor(acc.x, 32);
    acc.y += __shfl_xor(acc.y, 32);
    acc.z += __shfl_xor(acc.z, 32);
    acc.w += __shfl_xor(acc.w, 32);
    if (half == 0) {
        ushort4 o;
        o.x = f2bf(fmaxf(acc.x, 0.f));
        o.y = f2bf(fmaxf(acc.y, 0.f));
        o.z = f2bf(fmaxf(acc.z, 0.f));
        o.w = f2bf(fmaxf(acc.w, 0.f));
        *(ushort4*)(agg + (size_t)w * DH + c) = o;
    }
}

// ---------------- GEMM2 (bf16 MFMA): h2[NN,40](bf16) = agg[NN,128](bf16) @ W2[128,40] ----
__global__ __launch_bounds__(256) void gemm2_kernel(const __bf16* __restrict__ agg,
                                                    const float* __restrict__ W2,
                                                    __bf16* __restrict__ h2) {
    __shared__ __bf16 Wt2[48][136];   // [n][k], 13 KB
    const int t = threadIdx.x;
    const int wave = t >> 6, lane = t & 63;
    const int q = lane >> 4, m = lane & 15;
    const int row0 = blockIdx.x * 64 + wave * 16;
    for (int i = t; i < DH * DO; i += 256) {       // W2[k][n] f32 -> Wt2[n][k] bf16
        const int k = i / DO, n = i % DO;
        Wt2[n][k] = (__bf16)W2[i];
    }
    for (int i = t; i < 8 * DH; i += 256)          // zero-pad n in [40,48)
        Wt2[DO + (i >> 7)][i & 127] = (__bf16)0.f;
    __syncthreads();
    const int r = row0 + m;
    const bool okA = r < NN;
    const __bf16* ap = agg + (size_t)r * DH;
    f32x4 acc[3];
    #pragma unroll
    for (int nt = 0; nt < 3; ++nt)
        #pragma unroll
        for (int rr = 0; rr < 4; ++rr) acc[nt][rr] = 0.f;
    #pragma unroll
    for (int ks = 0; ks < 4; ++ks) {
        const int k0 = ks * 32 + q * 8;
        const bf16x8 a = okA ? *(const bf16x8*)(ap + k0) : bf16x8_zero();
        #pragma unroll
        for (int nt = 0; nt < 3; ++nt) {
            const bf16x8 b = *(const bf16x8*)(&Wt2[nt * 16 + m][k0]);
            acc[nt] = __builtin_amdgcn_mfma_f32_16x16x32_bf16(a, b, acc[nt], 0, 0, 0);
        }
    }
    #pragma unroll
    for (int reg = 0; reg < 4; ++reg) {
        const int rr = row0 + q * 4 + reg;
        if (rr < NN) {
            #pragma unroll
            for (int nt = 0; nt < 3; ++nt) {
                const int cc = nt * 16 + m;
                if (cc < DO) h2[(size_t)rr * DO + cc] = (__bf16)acc[nt][reg];
            }
        }
    }
}

// ---------------- Agg2: out[n](f32) = sum h2[src_e], d=40 ----------------
__global__ __launch_bounds__(256) void agg2_kernel(const __bf16* __restrict__ h2,
                                                   const int* __restrict__ esrc,
                                                   const int* __restrict__ off,
                                                   float* __restrict__ out) {
    const int w = (blockIdx.x * 256 + threadIdx.x) >> 6;
    if (w >= NN) return;
    const int lane = threadIdx.x & 63;
    const int sub = lane / 10;          // 0..5 active, lanes 60..63 idle
    const int c = (lane % 10) * 4;
    const int b = off[w], e = off[w + 1];
    float4 a0 = make_float4(0.f, 0.f, 0.f, 0.f);
    float4 a1 = a0, a2 = a0;
    if (sub < 6) {
        int j = b + sub;
        for (; j + 12 < e; j += 18) {
            const int s0 = esrc[j], s1 = esrc[j + 6], s2 = esrc[j + 12];
            const float4 v0 = bf4_to_f4(*(const ushort4*)(h2 + (size_t)s0 * DO + c));
            const float4 v1 = bf4_to_f4(*(const ushort4*)(h2 + (size_t)s1 * DO + c));
            const float4 v2 = bf4_to_f4(*(const ushort4*)(h2 + (size_t)s2 * DO + c));
            a0.x += v0.x; a0.y += v0.y; a0.z += v0.z; a0.w += v0.w;
            a1.x += v1.x; a1.y += v1.y; a1.z += v1.z; a1.w += v1.w;
            a2.x += v2.x; a2.y += v2.y; a2.z += v2.z; a2.w += v2.w;
        }
        for (; j < e; j += 6) {
            const int s = esrc[j];
            const float4 v = bf4_to_f4(*(const ushort4*)(h2 + (size_t)s * DO + c));
            a0.x += v.x; a0.y += v.y; a0.z += v.z; a0.w += v.w;
        }
    }
    float4 acc = make_float4(a0.x + a1.x + a2.x, a0.y + a1.y + a2.y,
                             a0.z + a1.z + a2.z, a0.w + a1.w + a2.w);
    acc.x += __shfl(acc.x, lane + 30);
    acc.y += __shfl(acc.y, lane + 30);
    acc.z += __shfl(acc.z, lane + 30);
    acc.w += __shfl(acc.w, lane + 30);
    const float ax = acc.x + __shfl(acc.x, lane + 10) + __shfl(acc.x, lane + 20);
    const float ay = acc.y + __shfl(acc.y, lane + 10) + __shfl(acc.y, lane + 20);
    const float az = acc.z + __shfl(acc.z, lane + 10) + __shfl(acc.z, lane + 20);
    const float aw = acc.w + __shfl(acc.w, lane + 10) + __shfl(acc.w, lane + 20);
    if (lane < 10) {
        *(float4*)(out + (size_t)w * DO + c) = make_float4(ax, ay, az, aw);
    }
}

extern "C" void kernel_launch(void* const* d_in, const int* in_sizes, int n_in,
                              void* d_out, int out_size, void* d_ws, size_t ws_size,
                              hipStream_t stream) {
    const float* x  = (const float*)d_in[0];
    const int*   ei = (const int*)d_in[1];
    const float* W1 = (const float*)d_in[2];
    const float* W2 = (const float*)d_in[3];
    const int* src = ei;
    const int* dst = ei + NE;

    __bf16* Wf  = (__bf16*)d_ws;                     // 32768 bf16 = 64 KB (packed W1 frags)
    __bf16* h1  = Wf + 32768;                        // NN*128 bf16 = 25.6 MB
    __bf16* agg = h1 + (size_t)NN * DH;              // NN*128 bf16 = 25.6 MB
    __bf16* h2  = h1;                                // NN*40 bf16 (aliases h1; dead after agg1)
    unsigned* epack = (unsigned*)(agg + (size_t)NN * DH);  // NE uint = 6.4 MB
    int* ints   = (int*)(epack + NE);
    int* esrc   = ints;                              // NE
    int* off    = esrc + NE;                         // NN+1
    int* hist2d = off + NN + 1;                      // M2
    int* offs2d = hist2d + M2;                       // M2
    int* bsum   = offs2d + M2;                       // NBS
    int* boff   = bsum + NBS;                        // NBS

    float* out = (float*)d_out;

    w1pack_kernel<<<128, 256, 0, stream>>>(W1, Wf);
    gemm1_kernel<<<(NN + 63) / 64, 256, 0, stream>>>(x, Wf, h1);
    bucket_hist_kernel<<<NB_BLK, 256, 0, stream>>>(dst, hist2d);
    spart_kernel<<<NBS, 256, 0, stream>>>(hist2d, bsum);
    sblock_kernel<<<1, 64, 0, stream>>>(bsum, boff);
    sfinal_kernel<<<NBS, 256, 0, stream>>>(hist2d, boff, offs2d);
    bucket_scatter_kernel<<<NB_BLK, 256, 0, stream>>>(src, dst, offs2d, epack);
    bucket_sort_kernel<<<NB, 256, 0, stream>>>(epack, offs2d, off, esrc);
    agg1_kernel<<<(NN * 64 + 255) / 256, 256, 0, stream>>>(h1, esrc, off, agg);
    gemm2_kernel<<<(NN + 63) / 64, 256, 0, stream>>>(agg, W2, h2);
    agg2_kernel<<<(NN * 64 + 255) / 256, 256, 0, stream>>>(h2, esrc, off, out);
}